// Round 13
// baseline (204.758 us; speedup 1.0000x reference)
//
#include <hip/hip_runtime.h>
#include <hip/hip_bf16.h>
#include <math.h>

typedef __attribute__((ext_vector_type(8)))  __bf16 bf16x8;
typedef __attribute__((ext_vector_type(4)))  __bf16 bf16x4;
typedef __attribute__((ext_vector_type(4)))  float  f32x4;
typedef __attribute__((ext_vector_type(16))) float  f32x16;

static constexpr int T_SEQ = 4096;
static constexpr int DM    = 1024;
static constexpr int NH    = 16;
// chunking: q-tile qb is split into nc = ceil((qb+1)/22) kv-chunks (1,2,3)
static constexpr int C2_QB    = 22;                   // first 2-chunk q-tile
static constexpr int C3_QB    = 44;                   // first 3-chunk q-tile
static constexpr int SPL_ROWS = T_SEQ - C2_QB * 64;   // 2688 rows needing combine
static constexpr int C3_ROWS  = T_SEQ - C3_QB * 64;   // 1280 rows with a 3rd chunk
static constexpr int NY = 126;                        // 22 + 22*2 + 20*3
// 1/sqrt(dk) * log2(e): softmax done in exp2 domain
static constexpr float QSCALE = 0.125f * 1.44269504088896340736f;

__device__ __forceinline__ void gload16(const void* g, void* l) {
    __builtin_amdgcn_global_load_lds(
        (const __attribute__((address_space(1))) unsigned int*)g,
        (__attribute__((address_space(3))) unsigned int*)l,
        16, 0, 0);
}

__device__ __forceinline__ unsigned cvtpk_bf16(float a, float b) {
    unsigned r;
    asm("v_cvt_pk_bf16_f32 %0, %1, %2" : "=v"(r) : "v"(a), "v"(b));
    return r;
}
// v_permlane32_swap_b32: exchanges lane<32 / lane>=32 halves between x and y
__device__ __forceinline__ void permswap(unsigned& x, unsigned& y) {
    asm("v_permlane32_swap_b32 %0, %1" : "+v"(x), "+v"(y));
}
// cross-half (lane^32) reduce. The empty asm keeps b a distinct SSA value so
// the allocator cannot coalesce a/b into one VGPR (round-5 NaN bug).
__device__ __forceinline__ float xhalf_max(float v) {
    union { float f; unsigned u; } a, b;
    a.f = v; b.f = v;
    asm volatile("" : "+v"(b.u));
    permswap(a.u, b.u);
    return fmaxf(a.f, b.f);
}
__device__ __forceinline__ float xhalf_sum(float v) {
    union { float f; unsigned u; } a, b;
    a.f = v; b.f = v;
    asm volatile("" : "+v"(b.u));
    permswap(a.u, b.u);
    return a.f + b.f;
}

// ---------------- fp32 -> bf16 converts ----------------
__global__ __launch_bounds__(256)
void cvt_bf16(const float* __restrict__ in, __bf16* __restrict__ out, int n4) {
    int i = blockIdx.x * blockDim.x + threadIdx.x;
    if (i >= n4) return;
    float4 v = ((const float4*)in)[i];
    bf16x4 o;
    o[0] = (__bf16)v.x; o[1] = (__bf16)v.y; o[2] = (__bf16)v.z; o[3] = (__bf16)v.w;
    ((bf16x4*)out)[i] = o;
}

__global__ __launch_bounds__(256)
void cvt4_bf16(const float* __restrict__ a0, const float* __restrict__ a1,
               const float* __restrict__ a2, const float* __restrict__ a3,
               __bf16* __restrict__ o0, __bf16* __restrict__ o1,
               __bf16* __restrict__ o2, __bf16* __restrict__ o3, int n4) {
    int i = blockIdx.x * blockDim.x + threadIdx.x;
    if (i >= n4) return;
    const float* in = blockIdx.y == 0 ? a0 : blockIdx.y == 1 ? a1 : blockIdx.y == 2 ? a2 : a3;
    __bf16* out     = blockIdx.y == 0 ? o0 : blockIdx.y == 1 ? o1 : blockIdx.y == 2 ? o2 : o3;
    float4 v = ((const float4*)in)[i];
    bf16x4 o;
    o[0] = (__bf16)v.x; o[1] = (__bf16)v.y; o[2] = (__bf16)v.z; o[3] = (__bf16)v.w;
    ((bf16x4*)out)[i] = o;
}

// ---------------- GEMM body: C = A @ B^T (m97 structure) ----------------
template<bool OUT_BF16>
__device__ __forceinline__ void gemm_body(const __bf16* __restrict__ A,
                                          const __bf16* __restrict__ B,
                                          void* __restrict__ Cout,
                                          int N, int K, float scale,
                                          int bx, int by) {
    __shared__ __align__(16) __bf16 Al[128 * 64];
    __shared__ __align__(16) __bf16 Bl[128 * 64];
    const int tid  = threadIdx.x;
    const int lane = tid & 63;
    const int wid  = tid >> 6;
    const int wr   = wid >> 1, wc = wid & 1;
    const int m0   = by * 128, n0 = bx * 128;
    const int r    = lane & 15, g = lane >> 4;

    f32x4 acc[4][4];
    const f32x4 z4 = {0.f, 0.f, 0.f, 0.f};
    #pragma unroll
    for (int i = 0; i < 4; ++i)
        #pragma unroll
        for (int j = 0; j < 4; ++j) acc[i][j] = z4;

    for (int kt = 0; kt < K; kt += 64) {
        __syncthreads();
        #pragma unroll
        for (int p = 0; p < 4; ++p) {
            int u    = p * 256 + tid;
            int row  = u >> 3;
            int col8 = (u & 7) ^ (row & 7);
            gload16(A + (size_t)(m0 + row) * K + kt + col8 * 8,
                    (char*)Al + (p * 256 + wid * 64) * 16);
            gload16(B + (size_t)(n0 + row) * K + kt + col8 * 8,
                    (char*)Bl + (p * 256 + wid * 64) * 16);
        }
        __syncthreads();
        __builtin_amdgcn_s_setprio(1);
        #pragma unroll
        for (int kk = 0; kk < 2; ++kk) {
            bf16x8 af[4], bfr[4];
            #pragma unroll
            for (int mi = 0; mi < 4; ++mi)
                af[mi] = *(const bf16x8*)&Al[(wr * 64 + mi * 16 + r) * 64 + (((kk * 4 + g) ^ (r & 7)) * 8)];
            #pragma unroll
            for (int nj = 0; nj < 4; ++nj)
                bfr[nj] = *(const bf16x8*)&Bl[(wc * 64 + nj * 16 + r) * 64 + (((kk * 4 + g) ^ (r & 7)) * 8)];
            #pragma unroll
            for (int mi = 0; mi < 4; ++mi)
                #pragma unroll
                for (int nj = 0; nj < 4; ++nj)
                    acc[mi][nj] = __builtin_amdgcn_mfma_f32_16x16x32_bf16(af[mi], bfr[nj], acc[mi][nj], 0, 0, 0);
        }
        __builtin_amdgcn_s_setprio(0);
    }
    #pragma unroll
    for (int mi = 0; mi < 4; ++mi)
        #pragma unroll
        for (int nj = 0; nj < 4; ++nj)
            #pragma unroll
            for (int j = 0; j < 4; ++j) {
                int row = m0 + wr * 64 + mi * 16 + g * 4 + j;
                int col = n0 + wc * 64 + nj * 16 + r;
                float v = acc[mi][nj][j] * scale;
                if (OUT_BF16) ((__bf16*)Cout)[(size_t)row * N + col] = (__bf16)v;
                else          ((float*)Cout)[(size_t)row * N + col]  = v;
            }
}

__global__ __launch_bounds__(256)
void gemm_qkv(const __bf16* __restrict__ A,
              const __bf16* __restrict__ W0, const __bf16* __restrict__ W1,
              const __bf16* __restrict__ W2,
              __bf16* __restrict__ O0, __bf16* __restrict__ O1, __bf16* __restrict__ O2) {
    const int z = blockIdx.z;
    const __bf16* B = z == 0 ? W0 : (z == 1 ? W1 : W2);
    __bf16*       C = z == 0 ? O0 : (z == 1 ? O1 : O2);
    float scale = z == 0 ? QSCALE : 1.0f;
    gemm_body<true>(A, B, C, DM, DM, scale, blockIdx.x, blockIdx.y);
}

__global__ __launch_bounds__(256)
void gemm_out(const __bf16* __restrict__ A, const __bf16* __restrict__ B,
              float* __restrict__ C) {
    gemm_body<false>(A, B, C, DM, DM, 1.0f, blockIdx.x, blockIdx.y);
}

// ---------------- V transpose: Vt[h*64+d][t] = V[t][h*64+d] ----------------
__global__ __launch_bounds__(256)
void vtrans(const __bf16* __restrict__ V, __bf16* __restrict__ Vt) {
    __shared__ __bf16 tl[64][72];
    const int tid = threadIdx.x;
    const int t0  = blockIdx.x * 64;
    const int h   = blockIdx.y;
    #pragma unroll
    for (int p = 0; p < 2; ++p) {
        int c = p * 256 + tid, row = c >> 3, col8 = c & 7;
        *(bf16x8*)&tl[row][col8 * 8] =
            *(const bf16x8*)(V + (size_t)(t0 + row) * DM + h * 64 + col8 * 8);
    }
    __syncthreads();
    #pragma unroll
    for (int p = 0; p < 2; ++p) {
        int c = p * 256 + tid, d = c >> 3, tc8 = c & 7;
        bf16x8 o;
        #pragma unroll
        for (int e = 0; e < 8; ++e) o[e] = tl[tc8 * 8 + e][d];
        *(bf16x8*)(Vt + (size_t)(h * 64 + d) * T_SEQ + t0 + tc8 * 8) = o;
    }
}

// ---------------- causal flash attention v13 ----------------
// = EXACT round-10 body (102us proven: reg-staged prefetch, QK(t+1) overlap,
// max-tracking softmax, 3-way chunk dispatch) with ONE change: V is a single
// LDS buffer (V(t) is read in D and rewritten in E between two barriers, so
// the second buffer was waste). LDS 32->24 KB => 6 blocks/CU instead of 5.
// Pipeline retimed: A issues K(t+2)->kreg and V(t+1)->vreg; E commits both.
__global__ __launch_bounds__(128)
void attn_fwd(const __bf16* __restrict__ Q, const __bf16* __restrict__ Kp,
              const __bf16* __restrict__ Vt, __bf16* __restrict__ O,
              __bf16* __restrict__ U0, __bf16* __restrict__ U1,
              __bf16* __restrict__ U2, float* __restrict__ Ml)
{
    __shared__ __align__(16) __bf16 Kl[2][64 * 64];
    __shared__ __align__(16) __bf16 Vl[64 * 64];
    const int tid  = threadIdx.x;
    const int lane = tid & 63, wid = tid >> 6;
    const int l31  = lane & 31;
    const int hi   = lane >> 5;
    const int h    = blockIdx.x;                 // head fastest -> XCD spread
    const int y    = blockIdx.y;                 // heavy chunks dispatched first
    int qb, chunk, nc;
    if (y < 60)       { qb = 63 - y / 3;        chunk = y % 3;        nc = 3; }
    else if (y < 104) { int s = y - 60; qb = 43 - s / 2; chunk = s % 2; nc = 2; }
    else              { qb = 21 - (y - 104);    chunk = 0;            nc = 1; }
    const int n    = qb + 1;
    const int base = n / nc, rem = n % nc;
    const int t0i  = chunk * base + (chunk < rem ? chunk : rem);
    const int t1i  = t0i + base + (chunk < rem ? 1 : 0) - 1;
    const int qw = qb * 64 + wid * 32;           // wave's first q row
    const int qg = qw + l31;                     // this lane's q row

    // Q fragments (B-operand): qf[kd0] = Q[qg][kd0*16 + hi*8 .. +7]
    bf16x8 qf[4];
    #pragma unroll
    for (int kd0 = 0; kd0 < 4; ++kd0)
        qf[kd0] = *(const bf16x8*)(Q + (size_t)qg * DM + h * 64 + kd0 * 16 + hi * 8);

    float m_i = -1e30f, l_i = 0.f;
    f32x16 oacc[2];
    #pragma unroll
    for (int d = 0; d < 2; ++d)
        #pragma unroll
        for (int e = 0; e < 16; ++e) oacc[d][e] = 0.f;

    // prologue staging via global_load_lds
    auto stageK_lds = [&](int t, int buf) {
        #pragma unroll
        for (int p = 0; p < 4; ++p) {
            int u    = p * 128 + tid;          // 16B unit, 0..511
            int row  = u >> 3;
            int col8 = (u & 7) ^ (row & 7);
            gload16(Kp + (size_t)(t * 64 + row) * DM + h * 64 + col8 * 8,
                    (char*)&Kl[buf][0] + (p * 128 + wid * 64) * 16);
        }
    };
    auto stageV_lds = [&](int t) {
        #pragma unroll
        for (int p = 0; p < 4; ++p) {
            int u    = p * 128 + tid;
            int row  = u >> 3;
            int col8 = (u & 7) ^ (row & 7);
            gload16(Vt + (size_t)(h * 64 + row) * T_SEQ + t * 64 + col8 * 8,
                    (char*)&Vl[0] + (p * 128 + wid * 64) * 16);
        }
    };
    stageK_lds(t0i, 0);
    stageV_lds(t0i);
    if (t1i > t0i) stageK_lds(t0i + 1, 1);
    __syncthreads();

    auto qk = [&](f32x16* sdst, int buf) {
        #pragma unroll
        for (int ksub = 0; ksub < 2; ++ksub) {
            const int row = ksub * 32 + l31;
            f32x16 a;
            #pragma unroll
            for (int e = 0; e < 16; ++e) a[e] = 0.f;
            #pragma unroll
            for (int kd0 = 0; kd0 < 4; ++kd0) {
                bf16x8 kf = *(const bf16x8*)
                    &Kl[buf][(row << 6) + ((((kd0 << 1) + hi) ^ (row & 7)) << 3)];
                a = __builtin_amdgcn_mfma_f32_32x32x16_bf16(kf, qf[kd0], a, 0, 0, 0);
            }
            sdst[ksub] = a;
        }
    };
    auto mask_sf = [&](f32x16* s, int t) {
        const int kb = (t << 6) + 4 * hi;
        #pragma unroll
        for (int ksub = 0; ksub < 2; ++ksub)
            #pragma unroll
            for (int e = 0; e < 16; ++e) {
                int k = kb + ksub * 32 + ((e & 3) + 8 * (e >> 2));
                if (k > qg) s[ksub][e] = -1e30f;
            }
    };

    // sf holds S(t) at loop top; Kl[cur^1]=K(t+1); Vl=V(t)
    f32x16 sf[2], sfn[2];
    qk(sf, 0);
    if (t0i == qb) mask_sf(sf, t0i);

    bf16x8 kreg[4], vreg[4];
    for (int t = t0i; t <= t1i; ++t) {
        const int cur = (t - t0i) & 1;
        const bool have_next  = (t + 1 <= t1i);
        const bool have_next2 = (t + 2 <= t1i);
        // A) issue reg-staged loads: K(t+2), V(t+1) (in flight across body)
        if (have_next2) {
            const int t2 = t + 2;
            #pragma unroll
            for (int p = 0; p < 4; ++p) {
                int u   = p * 128 + tid;
                int row = u >> 3;
                int c   = u & 7;
                kreg[p] = *(const bf16x8*)(Kp + (size_t)(t2 * 64 + row) * DM + h * 64 + c * 8);
            }
        }
        if (have_next) {
            const int t1 = t + 1;
            #pragma unroll
            for (int p = 0; p < 4; ++p) {
                int u   = p * 128 + tid;
                int row = u >> 3;
                int c   = u & 7;
                vreg[p] = *(const bf16x8*)(Vt + (size_t)(h * 64 + row) * T_SEQ + t1 * 64 + c * 8);
            }
        }
        // B) QK(t+1) — MFMA, independent of softmax(t)
        __builtin_amdgcn_s_setprio(1);
        if (have_next) {
            qk(sfn, cur ^ 1);
            if (t + 1 == qb) mask_sf(sfn, t + 1);
        }
        __builtin_amdgcn_s_setprio(0);
        // C) softmax(t) — VALU
        float pm;
        {
            float t0[8];
            #pragma unroll
            for (int e = 0; e < 8; ++e)
                t0[e] = fmaxf(fmaxf(sf[0][e], sf[0][e + 8]), fmaxf(sf[1][e], sf[1][e + 8]));
            #pragma unroll
            for (int s = 4; s > 0; s >>= 1)
                #pragma unroll
                for (int e = 0; e < s; ++e) t0[e] = fmaxf(t0[e], t0[e + s]);
            pm = xhalf_max(t0[0]);
        }
        if (pm > m_i + 8.f) {               // defer-max rescale
            float al = exp2f(m_i - pm);
            m_i = pm;
            l_i *= al;
            #pragma unroll
            for (int d = 0; d < 2; ++d)
                #pragma unroll
                for (int e = 0; e < 16; ++e) oacc[d][e] *= al;
        }
        float p[32];
        #pragma unroll
        for (int i = 0; i < 32; ++i)
            p[i] = exp2f(sf[i >> 4][i & 15] - m_i);
        {
            float s0[8];
            #pragma unroll
            for (int e = 0; e < 8; ++e)
                s0[e] = (p[e] + p[e + 8]) + (p[e + 16] + p[e + 24]);
            #pragma unroll
            for (int s = 4; s > 0; s >>= 1)
                #pragma unroll
                for (int e = 0; e < s; ++e) s0[e] += s0[e + s];
            l_i += xhalf_sum(s0[0]);
        }
        // D) PV(t): P->bf16 frags (cvt_pk + permlane32_swap), O^T += V^T P^T
        __builtin_amdgcn_s_setprio(1);
        #pragma unroll
        for (int ks = 0; ks < 4; ++ks) {
            unsigned w0 = cvtpk_bf16(p[8 * ks + 0], p[8 * ks + 1]);
            unsigned w1 = cvtpk_bf16(p[8 * ks + 2], p[8 * ks + 3]);
            unsigned w2 = cvtpk_bf16(p[8 * ks + 4], p[8 * ks + 5]);
            unsigned w3 = cvtpk_bf16(p[8 * ks + 6], p[8 * ks + 7]);
            permswap(w0, w2);
            permswap(w1, w3);
            union { unsigned u[4]; bf16x8 v; } pu;
            pu.u[0] = w0; pu.u[1] = w1; pu.u[2] = w2; pu.u[3] = w3;
            #pragma unroll
            for (int dsub = 0; dsub < 2; ++dsub) {
                const int row = dsub * 32 + l31;
                bf16x8 vt = *(const bf16x8*)
                    &Vl[(row << 6) + ((((ks << 1) + hi) ^ (row & 7)) << 3)];
                oacc[dsub] = __builtin_amdgcn_mfma_f32_32x32x16_bf16(vt, pu.v, oacc[dsub], 0, 0, 0);
            }
        }
        __builtin_amdgcn_s_setprio(0);
        // E) commit K(t+2)->Kl[cur], V(t+1)->Vl once all reads this iter done
        if (have_next) {
            __syncthreads();
            if (have_next2) {
                #pragma unroll
                for (int p = 0; p < 4; ++p) {
                    int u   = p * 128 + tid;
                    int row = u >> 3;
                    int c   = u & 7;
                    *(bf16x8*)&Kl[cur][(row << 6) + ((c ^ (row & 7)) << 3)] = kreg[p];
                }
            }
            #pragma unroll
            for (int p = 0; p < 4; ++p) {
                int u   = p * 128 + tid;
                int row = u >> 3;
                int c   = u & 7;
                *(bf16x8*)&Vl[(row << 6) + ((c ^ (row & 7)) << 3)] = vreg[p];
            }
            __syncthreads();
            sf[0] = sfn[0];
            sf[1] = sfn[1];
        }
    }
    // ---- epilogue: transpose via per-wave LDS, store O (or U,m,l) ----
    __syncthreads();
    __bf16* ow = &Kl[0][0] + wid * 2048;   // per-wave [32 q][64 d], 16B-swizzled
    const float invl = (nc > 1) ? 1.0f : (1.f / l_i);
    #pragma unroll
    for (int dsub = 0; dsub < 2; ++dsub)
        #pragma unroll
        for (int e = 0; e < 16; ++e) {
            int d = dsub * 32 + ((e & 3) + 8 * (e >> 2)) + 4 * hi;
            float v = oacc[dsub][e] * invl;
            int bo = l31 * 128 + ((2 * d) ^ ((l31 & 7) << 4));
            *(__bf16*)((char*)ow + bo) = (__bf16)v;
        }
    if (nc == 1) {
        #pragma unroll
        for (int i = 0; i < 4; ++i) {
            int u  = hi * 4 + i;
            int bo = l31 * 128 + ((u * 16) ^ ((l31 & 7) << 4));
            bf16x8 v8 = *(const bf16x8*)((char*)ow + bo);
            *(bf16x8*)(O + (size_t)qg * DM + h * 64 + u * 8) = v8;
        }
    } else {
        __bf16* Uc = (chunk == 0) ? U0 : (chunk == 1) ? U1 : U2;
        const int rows  = (chunk == 2) ? C3_ROWS : SPL_ROWS;
        const int ridx  = qg - ((chunk == 2) ? C3_QB * 64 : C2_QB * 64);
        #pragma unroll
        for (int i = 0; i < 4; ++i) {
            int u  = hi * 4 + i;
            int bo = l31 * 128 + ((u * 16) ^ ((l31 & 7) << 4));
            bf16x8 v8 = *(const bf16x8*)((char*)ow + bo);
            *(bf16x8*)(Uc + ((size_t)h * rows + ridx) * 64 + u * 8) = v8;
        }
        if (hi == 0) {
            size_t off = (chunk == 0) ? ((size_t)h * SPL_ROWS + ridx)
                       : (chunk == 1) ? ((size_t)(NH + h) * SPL_ROWS + ridx)
                                      : ((size_t)2 * NH * SPL_ROWS + (size_t)h * C3_ROWS + ridx);
            float* mlp = Ml + off * 2;
            mlp[0] = m_i;
            mlp[1] = l_i;
        }
    }
}

// ---------------- combine 2 or 3 kv-chunks for split rows ----------------
__global__ __launch_bounds__(256)
void attn_combine(const __bf16* __restrict__ U0, const __bf16* __restrict__ U1,
                  const __bf16* __restrict__ U2, const float* __restrict__ Ml,
                  __bf16* __restrict__ O) {
    int gid = blockIdx.x * 256 + threadIdx.x;    // 0 .. SPL_ROWS*NH*8-1
    int rh  = gid >> 3;
    int e8  = gid & 7;
    int ridx = rh >> 4, h = rh & 15;             // ridx in [0, SPL_ROWS)
    int qg   = C2_QB * 64 + ridx;                // global q row
    bool has3 = (qg >= C3_QB * 64);
    const float* ml0 = Ml + ((size_t)h * SPL_ROWS + ridx) * 2;
    const float* ml1 = Ml + ((size_t)(NH + h) * SPL_ROWS + ridx) * 2;
    float m0 = ml0[0], l0 = ml0[1], m1 = ml1[0], l1 = ml1[1];
    float m2 = -1e30f, l2 = 0.f;
    if (has3) {
        const float* ml2 = Ml + ((size_t)2 * NH * SPL_ROWS
                                 + (size_t)h * C3_ROWS + (qg - C3_QB * 64)) * 2;
        m2 = ml2[0]; l2 = ml2[1];
    }
    float M  = fmaxf(fmaxf(m0, m1), m2);
    float s0 = exp2f(m0 - M), s1 = exp2f(m1 - M);
    float s2 = has3 ? exp2f(m2 - M) : 0.f;
    float inv = 1.f / (l0 * s0 + l1 * s1 + l2 * s2);
    bf16x8 u0 = *(const bf16x8*)(U0 + ((size_t)h * SPL_ROWS + ridx) * 64 + e8 * 8);
    bf16x8 u1 = *(const bf16x8*)(U1 + ((size_t)h * SPL_ROWS + ridx) * 64 + e8 * 8);
    bf16x8 o;
    if (has3) {
        bf16x8 u2 = *(const bf16x8*)(U2 + ((size_t)h * C3_ROWS + (qg - C3_QB * 64)) * 64 + e8 * 8);
        #pragma unroll
        for (int j = 0; j < 8; ++j)
            o[j] = (__bf16)((((float)u0[j] * s0 + (float)u1[j] * s1) + (float)u2[j] * s2) * inv);
    } else {
        #pragma unroll
        for (int j = 0; j < 8; ++j)
            o[j] = (__bf16)(((float)u0[j] * s0 + (float)u1[j] * s1) * inv);
    }
    *(bf16x8*)(O + (size_t)qg * DM + h * 64 + e8 * 8) = o;
}

extern "C" void kernel_launch(void* const* d_in, const int* in_sizes, int n_in,
                              void* d_out, int out_size, void* d_ws, size_t ws_size,
                              hipStream_t stream) {
    const float* x  = (const float*)d_in[0];
    const float* Wq = (const float*)d_in[1];
    const float* Wk = (const float*)d_in[2];
    const float* Wv = (const float*)d_in[3];
    const float* Wo = (const float*)d_in[4];
    float* out = (float*)d_out;

    char* ws = (char*)d_ws;
    const size_t MB = (size_t)1 << 20;
    __bf16* xb    = (__bf16*)(ws + 0 * MB);    // 8 MiB (dead after QKV gemms)
    __bf16* U0B   = (__bf16*)(ws + 0 * MB);    // reuses xb: 5.25 MiB
    __bf16* wqb   = (__bf16*)(ws + 8 * MB);    // 2 MiB (dead after qkv)
    float*  MlB   = (float*)(ws + 8 * MB);     // reuses wqb: 0.85 MiB
    __bf16* wkb   = (__bf16*)(ws + 10 * MB);   // dead after qkv
    __bf16* U2B   = (__bf16*)(ws + 10 * MB);   // reuses wkb+wvb: 2.5 MiB
    __bf16* wvb   = (__bf16*)(ws + 12 * MB);
    __bf16* wob   = (__bf16*)(ws + 14 * MB);   // live until gemm_out
    __bf16* Qb    = (__bf16*)(ws + 16 * MB);
    __bf16* Kb    = (__bf16*)(ws + 24 * MB);
    __bf16* Vb    = (__bf16*)(ws + 32 * MB);   // dead after vtrans
    __bf16* U1B   = (__bf16*)(ws + 32 * MB);   // reuses Vb: 5.25 MiB
    __bf16* attnb = (__bf16*)(ws + 40 * MB);
    __bf16* VtR   = (__bf16*)(ws + 48 * MB);   // 8 MiB; total ws usage 56 MiB

    const int nX = T_SEQ * DM / 4;
    const int nW = DM * DM / 4;
    cvt_bf16<<<(nX + 255) / 256, 256, 0, stream>>>(x, xb, nX);
    cvt4_bf16<<<dim3((nW + 255) / 256, 4), 256, 0, stream>>>(Wq, Wk, Wv, Wo,
                                                             wqb, wkb, wvb, wob, nW);

    gemm_qkv<<<dim3(DM / 128, T_SEQ / 128, 3), 256, 0, stream>>>(xb, wqb, wkb, wvb, Qb, Kb, Vb);

    vtrans<<<dim3(T_SEQ / 64, NH), 256, 0, stream>>>(Vb, VtR);

    attn_fwd<<<dim3(NH, NY), 128, 0, stream>>>(Qb, Kb, VtR, attnb, U0B, U1B, U2B, MlB);

    attn_combine<<<(SPL_ROWS * NH * 8) / 256, 256, 0, stream>>>(U0B, U1B, U2B, MlB, attnb);

    gemm_out<<<dim3(DM / 128, T_SEQ / 128), 256, 0, stream>>>(attnb, wob, out);
}

// Round 14
// 202.818 us; speedup vs baseline: 1.0096x; 1.0096x over previous
//
#include <hip/hip_runtime.h>
#include <hip/hip_bf16.h>
#include <math.h>

typedef __attribute__((ext_vector_type(8)))  __bf16 bf16x8;
typedef __attribute__((ext_vector_type(4)))  __bf16 bf16x4;
typedef __attribute__((ext_vector_type(4)))  float  f32x4;
typedef __attribute__((ext_vector_type(16))) float  f32x16;

static constexpr int T_SEQ = 4096;
static constexpr int DM    = 1024;
static constexpr int NH    = 16;
// 4-wave blocks cover 128 q-rows (qblk 0..31). Block kv-work n = 2*qblk+2
// tiles, split into nc = ceil(n/22) chunks (1,2,3). Split rows start at
// qblk=11 -> row 1408 = C2_QB*64; 3-chunk rows at qblk=22 -> 2816 = C3_QB*64.
static constexpr int C2_QB    = 22;
static constexpr int C3_QB    = 44;
static constexpr int SPL_ROWS = T_SEQ - C2_QB * 64;   // 2688
static constexpr int C3_ROWS  = T_SEQ - C3_QB * 64;   // 1280
static constexpr int NY = 63;                         // 10*3 + 11*2 + 11
// 1/sqrt(dk) * log2(e): softmax done in exp2 domain
static constexpr float QSCALE = 0.125f * 1.44269504088896340736f;

__device__ __forceinline__ void gload16(const void* g, void* l) {
    __builtin_amdgcn_global_load_lds(
        (const __attribute__((address_space(1))) unsigned int*)g,
        (__attribute__((address_space(3))) unsigned int*)l,
        16, 0, 0);
}

__device__ __forceinline__ unsigned cvtpk_bf16(float a, float b) {
    unsigned r;
    asm("v_cvt_pk_bf16_f32 %0, %1, %2" : "=v"(r) : "v"(a), "v"(b));
    return r;
}
// v_permlane32_swap_b32: exchanges lane<32 / lane>=32 halves between x and y
__device__ __forceinline__ void permswap(unsigned& x, unsigned& y) {
    asm("v_permlane32_swap_b32 %0, %1" : "+v"(x), "+v"(y));
}
// cross-half (lane^32) reduce. The empty asm keeps b a distinct SSA value so
// the allocator cannot coalesce a/b into one VGPR (round-5 NaN bug).
__device__ __forceinline__ float xhalf_max(float v) {
    union { float f; unsigned u; } a, b;
    a.f = v; b.f = v;
    asm volatile("" : "+v"(b.u));
    permswap(a.u, b.u);
    return fmaxf(a.f, b.f);
}
__device__ __forceinline__ float xhalf_sum(float v) {
    union { float f; unsigned u; } a, b;
    a.f = v; b.f = v;
    asm volatile("" : "+v"(b.u));
    permswap(a.u, b.u);
    return a.f + b.f;
}

// ---------------- fp32 -> bf16 converts ----------------
__global__ __launch_bounds__(256)
void cvt_bf16(const float* __restrict__ in, __bf16* __restrict__ out, int n4) {
    int i = blockIdx.x * blockDim.x + threadIdx.x;
    if (i >= n4) return;
    float4 v = ((const float4*)in)[i];
    bf16x4 o;
    o[0] = (__bf16)v.x; o[1] = (__bf16)v.y; o[2] = (__bf16)v.z; o[3] = (__bf16)v.w;
    ((bf16x4*)out)[i] = o;
}

__global__ __launch_bounds__(256)
void cvt4_bf16(const float* __restrict__ a0, const float* __restrict__ a1,
               const float* __restrict__ a2, const float* __restrict__ a3,
               __bf16* __restrict__ o0, __bf16* __restrict__ o1,
               __bf16* __restrict__ o2, __bf16* __restrict__ o3, int n4) {
    int i = blockIdx.x * blockDim.x + threadIdx.x;
    if (i >= n4) return;
    const float* in = blockIdx.y == 0 ? a0 : blockIdx.y == 1 ? a1 : blockIdx.y == 2 ? a2 : a3;
    __bf16* out     = blockIdx.y == 0 ? o0 : blockIdx.y == 1 ? o1 : blockIdx.y == 2 ? o2 : o3;
    float4 v = ((const float4*)in)[i];
    bf16x4 o;
    o[0] = (__bf16)v.x; o[1] = (__bf16)v.y; o[2] = (__bf16)v.z; o[3] = (__bf16)v.w;
    ((bf16x4*)out)[i] = o;
}

// ---------------- GEMM body: C = A @ B^T (m97 structure) ----------------
template<bool OUT_BF16>
__device__ __forceinline__ void gemm_body(const __bf16* __restrict__ A,
                                          const __bf16* __restrict__ B,
                                          void* __restrict__ Cout,
                                          int N, int K, float scale,
                                          int bx, int by) {
    __shared__ __align__(16) __bf16 Al[128 * 64];
    __shared__ __align__(16) __bf16 Bl[128 * 64];
    const int tid  = threadIdx.x;
    const int lane = tid & 63;
    const int wid  = tid >> 6;
    const int wr   = wid >> 1, wc = wid & 1;
    const int m0   = by * 128, n0 = bx * 128;
    const int r    = lane & 15, g = lane >> 4;

    f32x4 acc[4][4];
    const f32x4 z4 = {0.f, 0.f, 0.f, 0.f};
    #pragma unroll
    for (int i = 0; i < 4; ++i)
        #pragma unroll
        for (int j = 0; j < 4; ++j) acc[i][j] = z4;

    for (int kt = 0; kt < K; kt += 64) {
        __syncthreads();
        #pragma unroll
        for (int p = 0; p < 4; ++p) {
            int u    = p * 256 + tid;
            int row  = u >> 3;
            int col8 = (u & 7) ^ (row & 7);
            gload16(A + (size_t)(m0 + row) * K + kt + col8 * 8,
                    (char*)Al + (p * 256 + wid * 64) * 16);
            gload16(B + (size_t)(n0 + row) * K + kt + col8 * 8,
                    (char*)Bl + (p * 256 + wid * 64) * 16);
        }
        __syncthreads();
        __builtin_amdgcn_s_setprio(1);
        #pragma unroll
        for (int kk = 0; kk < 2; ++kk) {
            bf16x8 af[4], bfr[4];
            #pragma unroll
            for (int mi = 0; mi < 4; ++mi)
                af[mi] = *(const bf16x8*)&Al[(wr * 64 + mi * 16 + r) * 64 + (((kk * 4 + g) ^ (r & 7)) * 8)];
            #pragma unroll
            for (int nj = 0; nj < 4; ++nj)
                bfr[nj] = *(const bf16x8*)&Bl[(wc * 64 + nj * 16 + r) * 64 + (((kk * 4 + g) ^ (r & 7)) * 8)];
            #pragma unroll
            for (int mi = 0; mi < 4; ++mi)
                #pragma unroll
                for (int nj = 0; nj < 4; ++nj)
                    acc[mi][nj] = __builtin_amdgcn_mfma_f32_16x16x32_bf16(af[mi], bfr[nj], acc[mi][nj], 0, 0, 0);
        }
        __builtin_amdgcn_s_setprio(0);
    }
    #pragma unroll
    for (int mi = 0; mi < 4; ++mi)
        #pragma unroll
        for (int nj = 0; nj < 4; ++nj)
            #pragma unroll
            for (int j = 0; j < 4; ++j) {
                int row = m0 + wr * 64 + mi * 16 + g * 4 + j;
                int col = n0 + wc * 64 + nj * 16 + r;
                float v = acc[mi][nj][j] * scale;
                if (OUT_BF16) ((__bf16*)Cout)[(size_t)row * N + col] = (__bf16)v;
                else          ((float*)Cout)[(size_t)row * N + col]  = v;
            }
}

__global__ __launch_bounds__(256)
void gemm_qkv(const __bf16* __restrict__ A,
              const __bf16* __restrict__ W0, const __bf16* __restrict__ W1,
              const __bf16* __restrict__ W2,
              __bf16* __restrict__ O0, __bf16* __restrict__ O1, __bf16* __restrict__ O2) {
    const int z = blockIdx.z;
    const __bf16* B = z == 0 ? W0 : (z == 1 ? W1 : W2);
    __bf16*       C = z == 0 ? O0 : (z == 1 ? O1 : O2);
    float scale = z == 0 ? QSCALE : 1.0f;
    gemm_body<true>(A, B, C, DM, DM, scale, blockIdx.x, blockIdx.y);
}

__global__ __launch_bounds__(256)
void gemm_out(const __bf16* __restrict__ A, const __bf16* __restrict__ B,
              float* __restrict__ C) {
    gemm_body<false>(A, B, C, DM, DM, 1.0f, blockIdx.x, blockIdx.y);
}

// ---------------- V transpose: Vt[h*64+d][t] = V[t][h*64+d] ----------------
__global__ __launch_bounds__(256)
void vtrans(const __bf16* __restrict__ V, __bf16* __restrict__ Vt) {
    __shared__ __bf16 tl[64][72];
    const int tid = threadIdx.x;
    const int t0  = blockIdx.x * 64;
    const int h   = blockIdx.y;
    #pragma unroll
    for (int p = 0; p < 2; ++p) {
        int c = p * 256 + tid, row = c >> 3, col8 = c & 7;
        *(bf16x8*)&tl[row][col8 * 8] =
            *(const bf16x8*)(V + (size_t)(t0 + row) * DM + h * 64 + col8 * 8);
    }
    __syncthreads();
    #pragma unroll
    for (int p = 0; p < 2; ++p) {
        int c = p * 256 + tid, d = c >> 3, tc8 = c & 7;
        bf16x8 o;
        #pragma unroll
        for (int e = 0; e < 8; ++e) o[e] = tl[tc8 * 8 + e][d];
        *(bf16x8*)(Vt + (size_t)(h * 64 + d) * T_SEQ + t0 + tc8 * 8) = o;
    }
}

// ---------------- causal flash attention v14 (4-wave blocks) ----------------
// Per-thread body is EXACTLY round-10's (proven 102us chassis: double-buffer
// K/V, reg-staged t+2, QK(t+1) overlap, max-tracking softmax). Change: 256
// threads / 4 waves per block covering 128 q-rows -> same 32 KB LDS amortized
// over 2x the waves => 16 waves/CU resident (was 10). kreg/vreg halve.
// Causal upper waves skip compute via wave-uniform haswork guard (barriers
// stay outside the guard).
__global__ __launch_bounds__(256)
void attn_fwd(const __bf16* __restrict__ Q, const __bf16* __restrict__ Kp,
              const __bf16* __restrict__ Vt, __bf16* __restrict__ O,
              __bf16* __restrict__ U0, __bf16* __restrict__ U1,
              __bf16* __restrict__ U2, float* __restrict__ Ml)
{
    __shared__ __align__(16) __bf16 Kl[2][64 * 64];
    __shared__ __align__(16) __bf16 Vl[2][64 * 64];
    const int tid  = threadIdx.x;
    const int lane = tid & 63, wid = tid >> 6;
    const int l31  = lane & 31;
    const int hi   = lane >> 5;
    const int h    = blockIdx.x;                 // head fastest -> XCD spread
    const int y    = blockIdx.y;                 // heavy chunks dispatched first
    int qblk, chunk, nc;
    if (y < 30)      { qblk = 31 - y / 3;       chunk = y % 3;        nc = 3; }
    else if (y < 52) { int s = y - 30; qblk = 21 - s / 2; chunk = s % 2; nc = 2; }
    else             { qblk = 10 - (y - 52);    chunk = 0;            nc = 1; }
    const int n    = 2 * qblk + 2;               // kv tiles for this block
    const int base = n / nc, rem = n % nc;
    const int t0i  = chunk * base + (chunk < rem ? chunk : rem);
    const int t1i  = t0i + base + (chunk < rem ? 1 : 0) - 1;
    const int qw   = qblk * 128 + wid * 32;      // wave's first q row
    const int qg   = qw + l31;                   // this lane's q row

    // Q fragments (B-operand): qf[kd0] = Q[qg][kd0*16 + hi*8 .. +7]
    bf16x8 qf[4];
    #pragma unroll
    for (int kd0 = 0; kd0 < 4; ++kd0)
        qf[kd0] = *(const bf16x8*)(Q + (size_t)qg * DM + h * 64 + kd0 * 16 + hi * 8);

    float m_i = -1e30f, l_i = 0.f;
    f32x16 oacc[2];
    #pragma unroll
    for (int d = 0; d < 2; ++d)
        #pragma unroll
        for (int e = 0; e < 16; ++e) oacc[d][e] = 0.f;

    // prologue: stage first (and second) tile via global_load_lds
    auto stage_lds = [&](int t, int buf) {
        #pragma unroll
        for (int p = 0; p < 2; ++p) {
            int u    = p * 256 + tid;          // 16B unit, 0..511
            int row  = u >> 3;
            int col8 = (u & 7) ^ (row & 7);
            gload16(Kp + (size_t)(t * 64 + row) * DM + h * 64 + col8 * 8,
                    (char*)&Kl[buf][0] + (p * 256 + wid * 64) * 16);
            gload16(Vt + (size_t)(h * 64 + row) * T_SEQ + t * 64 + col8 * 8,
                    (char*)&Vl[buf][0] + (p * 256 + wid * 64) * 16);
        }
    };
    stage_lds(t0i, 0);
    if (t1i > t0i) stage_lds(t0i + 1, 1);
    __syncthreads();

    auto qk = [&](f32x16* sdst, int buf) {
        #pragma unroll
        for (int ksub = 0; ksub < 2; ++ksub) {
            const int row = ksub * 32 + l31;
            f32x16 a;
            #pragma unroll
            for (int e = 0; e < 16; ++e) a[e] = 0.f;
            #pragma unroll
            for (int kd0 = 0; kd0 < 4; ++kd0) {
                bf16x8 kf = *(const bf16x8*)
                    &Kl[buf][(row << 6) + ((((kd0 << 1) + hi) ^ (row & 7)) << 3)];
                a = __builtin_amdgcn_mfma_f32_32x32x16_bf16(kf, qf[kd0], a, 0, 0, 0);
            }
            sdst[ksub] = a;
        }
    };
    auto mask_sf = [&](f32x16* s, int t) {
        const int kb = (t << 6) + 4 * hi;
        #pragma unroll
        for (int ksub = 0; ksub < 2; ++ksub)
            #pragma unroll
            for (int e = 0; e < 16; ++e) {
                int k = kb + ksub * 32 + ((e & 3) + 8 * (e >> 2));
                if (k > qg) s[ksub][e] = -1e30f;
            }
    };
    // wave has unmasked work in tile t iff tile start <= wave's last q row
    auto haswork = [&](int t) { return (t << 6) <= qw + 31; };

    // sf holds S(t) at loop top
    f32x16 sf[2], sfn[2];
    if (haswork(t0i)) {
        qk(sf, 0);
        if ((t0i << 6) + 63 > qw) mask_sf(sf, t0i);
    }

    bf16x8 kreg[2], vreg[2];
    for (int t = t0i; t <= t1i; ++t) {
        const int cur = (t - t0i) & 1;
        const bool have_next  = (t + 1 <= t1i);
        const bool have_next2 = (t + 2 <= t1i);
        // A) issue reg-staged loads for tile t+2 (in flight across whole body)
        if (have_next2) {
            const int t2 = t + 2;
            #pragma unroll
            for (int p = 0; p < 2; ++p) {
                int u   = p * 256 + tid;
                int row = u >> 3;
                int c   = u & 7;
                kreg[p] = *(const bf16x8*)(Kp + (size_t)(t2 * 64 + row) * DM + h * 64 + c * 8);
                vreg[p] = *(const bf16x8*)(Vt + (size_t)(h * 64 + row) * T_SEQ + t2 * 64 + c * 8);
            }
        }
        // B) QK(t+1) — MFMA, independent of softmax(t)
        __builtin_amdgcn_s_setprio(1);
        if (have_next && haswork(t + 1)) {
            qk(sfn, cur ^ 1);
            if (((t + 1) << 6) + 63 > qw) mask_sf(sfn, t + 1);
        }
        __builtin_amdgcn_s_setprio(0);
        if (haswork(t)) {
            // C) softmax(t) — VALU
            float pm;
            {
                float t0[8];
                #pragma unroll
                for (int e = 0; e < 8; ++e)
                    t0[e] = fmaxf(fmaxf(sf[0][e], sf[0][e + 8]), fmaxf(sf[1][e], sf[1][e + 8]));
                #pragma unroll
                for (int s = 4; s > 0; s >>= 1)
                    #pragma unroll
                    for (int e = 0; e < s; ++e) t0[e] = fmaxf(t0[e], t0[e + s]);
                pm = xhalf_max(t0[0]);
            }
            if (pm > m_i + 8.f) {               // defer-max rescale
                float al = exp2f(m_i - pm);
                m_i = pm;
                l_i *= al;
                #pragma unroll
                for (int d = 0; d < 2; ++d)
                    #pragma unroll
                    for (int e = 0; e < 16; ++e) oacc[d][e] *= al;
            }
            float p[32];
            #pragma unroll
            for (int i = 0; i < 32; ++i)
                p[i] = exp2f(sf[i >> 4][i & 15] - m_i);
            {
                float s0[8];
                #pragma unroll
                for (int e = 0; e < 8; ++e)
                    s0[e] = (p[e] + p[e + 8]) + (p[e + 16] + p[e + 24]);
                #pragma unroll
                for (int s = 4; s > 0; s >>= 1)
                    #pragma unroll
                    for (int e = 0; e < s; ++e) s0[e] += s0[e + s];
                l_i += xhalf_sum(s0[0]);
            }
            // D) PV(t): P->bf16 frags (cvt_pk + permlane32_swap), O^T += V^T P^T
            __builtin_amdgcn_s_setprio(1);
            #pragma unroll
            for (int ks = 0; ks < 4; ++ks) {
                unsigned w0 = cvtpk_bf16(p[8 * ks + 0], p[8 * ks + 1]);
                unsigned w1 = cvtpk_bf16(p[8 * ks + 2], p[8 * ks + 3]);
                unsigned w2 = cvtpk_bf16(p[8 * ks + 4], p[8 * ks + 5]);
                unsigned w3 = cvtpk_bf16(p[8 * ks + 6], p[8 * ks + 7]);
                permswap(w0, w2);
                permswap(w1, w3);
                union { unsigned u[4]; bf16x8 v; } pu;
                pu.u[0] = w0; pu.u[1] = w1; pu.u[2] = w2; pu.u[3] = w3;
                #pragma unroll
                for (int dsub = 0; dsub < 2; ++dsub) {
                    const int row = dsub * 32 + l31;
                    bf16x8 vt = *(const bf16x8*)
                        &Vl[cur][(row << 6) + ((((ks << 1) + hi) ^ (row & 7)) << 3)];
                    oacc[dsub] = __builtin_amdgcn_mfma_f32_32x32x16_bf16(vt, pu.v, oacc[dsub], 0, 0, 0);
                }
            }
            __builtin_amdgcn_s_setprio(0);
        }
        // E) commit tile t+2 into buf[cur] once all reads of buf[cur] are done
        if (have_next2) {
            __syncthreads();
            #pragma unroll
            for (int p = 0; p < 2; ++p) {
                int u   = p * 256 + tid;
                int row = u >> 3;
                int c   = u & 7;
                *(bf16x8*)&Kl[cur][(row << 6) + ((c ^ (row & 7)) << 3)] = kreg[p];
                *(bf16x8*)&Vl[cur][(row << 6) + ((c ^ (row & 7)) << 3)] = vreg[p];
            }
            __syncthreads();
        }
        if (have_next) {
            sf[0] = sfn[0];
            sf[1] = sfn[1];
        }
    }
    // ---- epilogue: transpose via per-wave LDS, store O (or U,m,l) ----
    __syncthreads();
    __bf16* ow = &Kl[0][0] + wid * 2048;   // per-wave [32 q][64 d], 16B-swizzled
    const float invl = (nc > 1) ? 1.0f : (1.f / l_i);
    #pragma unroll
    for (int dsub = 0; dsub < 2; ++dsub)
        #pragma unroll
        for (int e = 0; e < 16; ++e) {
            int d = dsub * 32 + ((e & 3) + 8 * (e >> 2)) + 4 * hi;
            float v = oacc[dsub][e] * invl;
            int bo = l31 * 128 + ((2 * d) ^ ((l31 & 7) << 4));
            *(__bf16*)((char*)ow + bo) = (__bf16)v;
        }
    if (nc == 1) {
        #pragma unroll
        for (int i = 0; i < 4; ++i) {
            int u  = hi * 4 + i;
            int bo = l31 * 128 + ((u * 16) ^ ((l31 & 7) << 4));
            bf16x8 v8 = *(const bf16x8*)((char*)ow + bo);
            *(bf16x8*)(O + (size_t)qg * DM + h * 64 + u * 8) = v8;
        }
    } else {
        __bf16* Uc = (chunk == 0) ? U0 : (chunk == 1) ? U1 : U2;
        const int rows  = (chunk == 2) ? C3_ROWS : SPL_ROWS;
        const int ridx  = qg - ((chunk == 2) ? C3_QB * 64 : C2_QB * 64);
        #pragma unroll
        for (int i = 0; i < 4; ++i) {
            int u  = hi * 4 + i;
            int bo = l31 * 128 + ((u * 16) ^ ((l31 & 7) << 4));
            bf16x8 v8 = *(const bf16x8*)((char*)ow + bo);
            *(bf16x8*)(Uc + ((size_t)h * rows + ridx) * 64 + u * 8) = v8;
        }
        if (hi == 0) {
            size_t off = (chunk == 0) ? ((size_t)h * SPL_ROWS + ridx)
                       : (chunk == 1) ? ((size_t)(NH + h) * SPL_ROWS + ridx)
                                      : ((size_t)2 * NH * SPL_ROWS + (size_t)h * C3_ROWS + ridx);
            float* mlp = Ml + off * 2;
            mlp[0] = m_i;
            mlp[1] = l_i;
        }
    }
}

// ---------------- combine 2 or 3 kv-chunks for split rows ----------------
__global__ __launch_bounds__(256)
void attn_combine(const __bf16* __restrict__ U0, const __bf16* __restrict__ U1,
                  const __bf16* __restrict__ U2, const float* __restrict__ Ml,
                  __bf16* __restrict__ O) {
    int gid = blockIdx.x * 256 + threadIdx.x;    // 0 .. SPL_ROWS*NH*8-1
    int rh  = gid >> 3;
    int e8  = gid & 7;
    int ridx = rh >> 4, h = rh & 15;             // ridx in [0, SPL_ROWS)
    int qg   = C2_QB * 64 + ridx;                // global q row
    bool has3 = (qg >= C3_QB * 64);
    const float* ml0 = Ml + ((size_t)h * SPL_ROWS + ridx) * 2;
    const float* ml1 = Ml + ((size_t)(NH + h) * SPL_ROWS + ridx) * 2;
    float m0 = ml0[0], l0 = ml0[1], m1 = ml1[0], l1 = ml1[1];
    float m2 = -1e30f, l2 = 0.f;
    if (has3) {
        const float* ml2 = Ml + ((size_t)2 * NH * SPL_ROWS
                                 + (size_t)h * C3_ROWS + (qg - C3_QB * 64)) * 2;
        m2 = ml2[0]; l2 = ml2[1];
    }
    float M  = fmaxf(fmaxf(m0, m1), m2);
    float s0 = exp2f(m0 - M), s1 = exp2f(m1 - M);
    float s2 = has3 ? exp2f(m2 - M) : 0.f;
    float inv = 1.f / (l0 * s0 + l1 * s1 + l2 * s2);
    bf16x8 u0 = *(const bf16x8*)(U0 + ((size_t)h * SPL_ROWS + ridx) * 64 + e8 * 8);
    bf16x8 u1 = *(const bf16x8*)(U1 + ((size_t)h * SPL_ROWS + ridx) * 64 + e8 * 8);
    bf16x8 o;
    if (has3) {
        bf16x8 u2 = *(const bf16x8*)(U2 + ((size_t)h * C3_ROWS + (qg - C3_QB * 64)) * 64 + e8 * 8);
        #pragma unroll
        for (int j = 0; j < 8; ++j)
            o[j] = (__bf16)((((float)u0[j] * s0 + (float)u1[j] * s1) + (float)u2[j] * s2) * inv);
    } else {
        #pragma unroll
        for (int j = 0; j < 8; ++j)
            o[j] = (__bf16)(((float)u0[j] * s0 + (float)u1[j] * s1) * inv);
    }
    *(bf16x8*)(O + (size_t)qg * DM + h * 64 + e8 * 8) = o;
}

extern "C" void kernel_launch(void* const* d_in, const int* in_sizes, int n_in,
                              void* d_out, int out_size, void* d_ws, size_t ws_size,
                              hipStream_t stream) {
    const float* x  = (const float*)d_in[0];
    const float* Wq = (const float*)d_in[1];
    const float* Wk = (const float*)d_in[2];
    const float* Wv = (const float*)d_in[3];
    const float* Wo = (const float*)d_in[4];
    float* out = (float*)d_out;

    char* ws = (char*)d_ws;
    const size_t MB = (size_t)1 << 20;
    __bf16* xb    = (__bf16*)(ws + 0 * MB);    // 8 MiB (dead after QKV gemms)
    __bf16* U0B   = (__bf16*)(ws + 0 * MB);    // reuses xb: 5.25 MiB
    __bf16* wqb   = (__bf16*)(ws + 8 * MB);    // 2 MiB (dead after qkv)
    float*  MlB   = (float*)(ws + 8 * MB);     // reuses wqb: 0.85 MiB
    __bf16* wkb   = (__bf16*)(ws + 10 * MB);   // dead after qkv
    __bf16* U2B   = (__bf16*)(ws + 10 * MB);   // reuses wkb+wvb: 2.5 MiB
    __bf16* wvb   = (__bf16*)(ws + 12 * MB);
    __bf16* wob   = (__bf16*)(ws + 14 * MB);   // live until gemm_out
    __bf16* Qb    = (__bf16*)(ws + 16 * MB);
    __bf16* Kb    = (__bf16*)(ws + 24 * MB);
    __bf16* Vb    = (__bf16*)(ws + 32 * MB);   // dead after vtrans
    __bf16* U1B   = (__bf16*)(ws + 32 * MB);   // reuses Vb: 5.25 MiB
    __bf16* attnb = (__bf16*)(ws + 40 * MB);
    __bf16* VtR   = (__bf16*)(ws + 48 * MB);   // 8 MiB; total ws usage 56 MiB

    const int nX = T_SEQ * DM / 4;
    const int nW = DM * DM / 4;
    cvt_bf16<<<(nX + 255) / 256, 256, 0, stream>>>(x, xb, nX);
    cvt4_bf16<<<dim3((nW + 255) / 256, 4), 256, 0, stream>>>(Wq, Wk, Wv, Wo,
                                                             wqb, wkb, wvb, wob, nW);

    gemm_qkv<<<dim3(DM / 128, T_SEQ / 128, 3), 256, 0, stream>>>(xb, wqb, wkb, wvb, Qb, Kb, Vb);

    vtrans<<<dim3(T_SEQ / 64, NH), 256, 0, stream>>>(Vb, VtR);

    attn_fwd<<<dim3(NH, NY), 256, 0, stream>>>(Qb, Kb, VtR, attnb, U0B, U1B, U2B, MlB);

    attn_combine<<<(SPL_ROWS * NH * 8) / 256, 256, 0, stream>>>(U0B, U1B, U2B, MlB, attnb);

    gemm_out<<<dim3(DM / 128, T_SEQ / 128), 256, 0, stream>>>(attnb, wob, out);
}

// Round 15
// 190.348 us; speedup vs baseline: 1.0757x; 1.0655x over previous
//
#include <hip/hip_runtime.h>
#include <hip/hip_bf16.h>
#include <math.h>

typedef __attribute__((ext_vector_type(8)))  __bf16 bf16x8;
typedef __attribute__((ext_vector_type(4)))  __bf16 bf16x4;
typedef __attribute__((ext_vector_type(4)))  float  f32x4;
typedef __attribute__((ext_vector_type(16))) float  f32x16;

static constexpr int T_SEQ = 4096;
static constexpr int DM    = 1024;
static constexpr int NH    = 16;
// chunking: q-tile qb is split into nc = ceil((qb+1)/22) kv-chunks (1,2,3)
static constexpr int C2_QB    = 22;                   // first 2-chunk q-tile
static constexpr int C3_QB    = 44;                   // first 3-chunk q-tile
static constexpr int SPL_ROWS = T_SEQ - C2_QB * 64;   // 2688 rows needing combine
static constexpr int C3_ROWS  = T_SEQ - C3_QB * 64;   // 1280 rows with a 3rd chunk
static constexpr int NY = 126;                        // 22 + 22*2 + 20*3
// 1/sqrt(dk) * log2(e): softmax done in exp2 domain
static constexpr float QSCALE = 0.125f * 1.44269504088896340736f;

__device__ __forceinline__ void gload16(const void* g, void* l) {
    __builtin_amdgcn_global_load_lds(
        (const __attribute__((address_space(1))) unsigned int*)g,
        (__attribute__((address_space(3))) unsigned int*)l,
        16, 0, 0);
}

__device__ __forceinline__ unsigned cvtpk_bf16(float a, float b) {
    unsigned r;
    asm("v_cvt_pk_bf16_f32 %0, %1, %2" : "=v"(r) : "v"(a), "v"(b));
    return r;
}
// v_permlane32_swap_b32: exchanges lane<32 / lane>=32 halves between x and y
__device__ __forceinline__ void permswap(unsigned& x, unsigned& y) {
    asm("v_permlane32_swap_b32 %0, %1" : "+v"(x), "+v"(y));
}
// cross-half (lane^32) reduce. The empty asm keeps b a distinct SSA value so
// the allocator cannot coalesce a/b into one VGPR (round-5 NaN bug).
__device__ __forceinline__ float xhalf_max(float v) {
    union { float f; unsigned u; } a, b;
    a.f = v; b.f = v;
    asm volatile("" : "+v"(b.u));
    permswap(a.u, b.u);
    return fmaxf(a.f, b.f);
}
__device__ __forceinline__ float xhalf_sum(float v) {
    union { float f; unsigned u; } a, b;
    a.f = v; b.f = v;
    asm volatile("" : "+v"(b.u));
    permswap(a.u, b.u);
    return a.f + b.f;
}

// ---------------- fp32 -> bf16 convert (x + 4 weights in one launch) -------
__global__ __launch_bounds__(256)
void cvt5_bf16(const float* __restrict__ a0, const float* __restrict__ a1,
               const float* __restrict__ a2, const float* __restrict__ a3,
               const float* __restrict__ a4,
               __bf16* __restrict__ o0, __bf16* __restrict__ o1,
               __bf16* __restrict__ o2, __bf16* __restrict__ o3,
               __bf16* __restrict__ o4, int nX4, int nW4) {
    int y = blockIdx.y;
    int n4 = (y == 0) ? nX4 : nW4;
    int i = blockIdx.x * blockDim.x + threadIdx.x;
    if (i >= n4) return;
    const float* in = y == 0 ? a0 : y == 1 ? a1 : y == 2 ? a2 : y == 3 ? a3 : a4;
    __bf16* out     = y == 0 ? o0 : y == 1 ? o1 : y == 2 ? o2 : y == 3 ? o3 : o4;
    float4 v = ((const float4*)in)[i];
    bf16x4 o;
    o[0] = (__bf16)v.x; o[1] = (__bf16)v.y; o[2] = (__bf16)v.z; o[3] = (__bf16)v.w;
    ((bf16x4*)out)[i] = o;
}

// ---------------- GEMM body: C = A @ B^T (m97 structure) ----------------
template<bool OUT_BF16>
__device__ __forceinline__ void gemm_body(const __bf16* __restrict__ A,
                                          const __bf16* __restrict__ B,
                                          void* __restrict__ Cout,
                                          int N, int K, float scale,
                                          int bx, int by) {
    __shared__ __align__(16) __bf16 Al[128 * 64];
    __shared__ __align__(16) __bf16 Bl[128 * 64];
    const int tid  = threadIdx.x;
    const int lane = tid & 63;
    const int wid  = tid >> 6;
    const int wr   = wid >> 1, wc = wid & 1;
    const int m0   = by * 128, n0 = bx * 128;
    const int r    = lane & 15, g = lane >> 4;

    f32x4 acc[4][4];
    const f32x4 z4 = {0.f, 0.f, 0.f, 0.f};
    #pragma unroll
    for (int i = 0; i < 4; ++i)
        #pragma unroll
        for (int j = 0; j < 4; ++j) acc[i][j] = z4;

    for (int kt = 0; kt < K; kt += 64) {
        __syncthreads();
        #pragma unroll
        for (int p = 0; p < 4; ++p) {
            int u    = p * 256 + tid;
            int row  = u >> 3;
            int col8 = (u & 7) ^ (row & 7);
            gload16(A + (size_t)(m0 + row) * K + kt + col8 * 8,
                    (char*)Al + (p * 256 + wid * 64) * 16);
            gload16(B + (size_t)(n0 + row) * K + kt + col8 * 8,
                    (char*)Bl + (p * 256 + wid * 64) * 16);
        }
        __syncthreads();
        __builtin_amdgcn_s_setprio(1);
        #pragma unroll
        for (int kk = 0; kk < 2; ++kk) {
            bf16x8 af[4], bfr[4];
            #pragma unroll
            for (int mi = 0; mi < 4; ++mi)
                af[mi] = *(const bf16x8*)&Al[(wr * 64 + mi * 16 + r) * 64 + (((kk * 4 + g) ^ (r & 7)) * 8)];
            #pragma unroll
            for (int nj = 0; nj < 4; ++nj)
                bfr[nj] = *(const bf16x8*)&Bl[(wc * 64 + nj * 16 + r) * 64 + (((kk * 4 + g) ^ (r & 7)) * 8)];
            #pragma unroll
            for (int mi = 0; mi < 4; ++mi)
                #pragma unroll
                for (int nj = 0; nj < 4; ++nj)
                    acc[mi][nj] = __builtin_amdgcn_mfma_f32_16x16x32_bf16(af[mi], bfr[nj], acc[mi][nj], 0, 0, 0);
        }
        __builtin_amdgcn_s_setprio(0);
    }
    #pragma unroll
    for (int mi = 0; mi < 4; ++mi)
        #pragma unroll
        for (int nj = 0; nj < 4; ++nj)
            #pragma unroll
            for (int j = 0; j < 4; ++j) {
                int row = m0 + wr * 64 + mi * 16 + g * 4 + j;
                int col = n0 + wc * 64 + nj * 16 + r;
                float v = acc[mi][nj][j] * scale;
                if (OUT_BF16) ((__bf16*)Cout)[(size_t)row * N + col] = (__bf16)v;
                else          ((float*)Cout)[(size_t)row * N + col]  = v;
            }
}

__global__ __launch_bounds__(256)
void gemm_qkv(const __bf16* __restrict__ A,
              const __bf16* __restrict__ W0, const __bf16* __restrict__ W1,
              const __bf16* __restrict__ W2,
              __bf16* __restrict__ O0, __bf16* __restrict__ O1, __bf16* __restrict__ O2) {
    const int z = blockIdx.z;
    const __bf16* B = z == 0 ? W0 : (z == 1 ? W1 : W2);
    __bf16*       C = z == 0 ? O0 : (z == 1 ? O1 : O2);
    float scale = z == 0 ? QSCALE : 1.0f;
    gemm_body<true>(A, B, C, DM, DM, scale, blockIdx.x, blockIdx.y);
}

__global__ __launch_bounds__(256)
void gemm_out(const __bf16* __restrict__ A, const __bf16* __restrict__ B,
              float* __restrict__ C) {
    gemm_body<false>(A, B, C, DM, DM, 1.0f, blockIdx.x, blockIdx.y);
}

// ---------------- V transpose: Vt[h*64+d][t] = V[t][h*64+d] ----------------
__global__ __launch_bounds__(256)
void vtrans(const __bf16* __restrict__ V, __bf16* __restrict__ Vt) {
    __shared__ __bf16 tl[64][72];
    const int tid = threadIdx.x;
    const int t0  = blockIdx.x * 64;
    const int h   = blockIdx.y;
    #pragma unroll
    for (int p = 0; p < 2; ++p) {
        int c = p * 256 + tid, row = c >> 3, col8 = c & 7;
        *(bf16x8*)&tl[row][col8 * 8] =
            *(const bf16x8*)(V + (size_t)(t0 + row) * DM + h * 64 + col8 * 8);
    }
    __syncthreads();
    #pragma unroll
    for (int p = 0; p < 2; ++p) {
        int c = p * 256 + tid, d = c >> 3, tc8 = c & 7;
        bf16x8 o;
        #pragma unroll
        for (int e = 0; e < 8; ++e) o[e] = tl[tc8 * 8 + e][d];
        *(bf16x8*)(Vt + (size_t)(h * 64 + d) * T_SEQ + t0 + tc8 * 8) = o;
    }
}

// ---------------- causal flash attention v15 ----------------
// = round-10 body (102.9us proven) with ONE LDS change: K is SINGLE-buffered
// (Kl read only in phase B for tile t+1, rewritten in E with t+2 after a
// barrier -> 2nd buffer was dead). V stays double-buffered; BOTH prefetches
// stay at t+2 distance (r13's mistake was shortening V to t+1). LDS 32->24KB
// => 6 blocks/CU (12 waves, +20% residency; LDS cap 12 holds for VGPR<=170).
__global__ __launch_bounds__(128)
void attn_fwd(const __bf16* __restrict__ Q, const __bf16* __restrict__ Kp,
              const __bf16* __restrict__ Vt, __bf16* __restrict__ O,
              __bf16* __restrict__ U0, __bf16* __restrict__ U1,
              __bf16* __restrict__ U2, float* __restrict__ Ml)
{
    __shared__ __align__(16) __bf16 Kl[64 * 64];
    __shared__ __align__(16) __bf16 Vl[2][64 * 64];
    const int tid  = threadIdx.x;
    const int lane = tid & 63, wid = tid >> 6;
    const int l31  = lane & 31;
    const int hi   = lane >> 5;
    const int h    = blockIdx.x;                 // head fastest -> XCD spread
    const int y    = blockIdx.y;                 // heavy chunks dispatched first
    int qb, chunk, nc;
    if (y < 60)       { qb = 63 - y / 3;        chunk = y % 3;        nc = 3; }
    else if (y < 104) { int s = y - 60; qb = 43 - s / 2; chunk = s % 2; nc = 2; }
    else              { qb = 21 - (y - 104);    chunk = 0;            nc = 1; }
    const int n    = qb + 1;
    const int base = n / nc, rem = n % nc;
    const int t0i  = chunk * base + (chunk < rem ? chunk : rem);
    const int t1i  = t0i + base + (chunk < rem ? 1 : 0) - 1;
    const int qw = qb * 64 + wid * 32;           // wave's first q row
    const int qg = qw + l31;                     // this lane's q row

    // Q fragments (B-operand): qf[kd0] = Q[qg][kd0*16 + hi*8 .. +7]
    bf16x8 qf[4];
    #pragma unroll
    for (int kd0 = 0; kd0 < 4; ++kd0)
        qf[kd0] = *(const bf16x8*)(Q + (size_t)qg * DM + h * 64 + kd0 * 16 + hi * 8);

    float m_i = -1e30f, l_i = 0.f;
    f32x16 oacc[2];
    #pragma unroll
    for (int d = 0; d < 2; ++d)
        #pragma unroll
        for (int e = 0; e < 16; ++e) oacc[d][e] = 0.f;

    bf16x8 kreg[4], vreg[4];
    // prologue staging via global_load_lds
    auto stageK_lds = [&](int t) {
        #pragma unroll
        for (int p = 0; p < 4; ++p) {
            int u    = p * 128 + tid;          // 16B unit, 0..511
            int row  = u >> 3;
            int col8 = (u & 7) ^ (row & 7);
            gload16(Kp + (size_t)(t * 64 + row) * DM + h * 64 + col8 * 8,
                    (char*)&Kl[0] + (p * 128 + wid * 64) * 16);
        }
    };
    auto stageV_lds = [&](int t, int buf) {
        #pragma unroll
        for (int p = 0; p < 4; ++p) {
            int u    = p * 128 + tid;
            int row  = u >> 3;
            int col8 = (u & 7) ^ (row & 7);
            gload16(Vt + (size_t)(h * 64 + row) * T_SEQ + t * 64 + col8 * 8,
                    (char*)&Vl[buf][0] + (p * 128 + wid * 64) * 16);
        }
    };
    auto ldK = [&](int t) {
        #pragma unroll
        for (int p = 0; p < 4; ++p) {
            int u = p * 128 + tid, row = u >> 3, c = u & 7;
            kreg[p] = *(const bf16x8*)(Kp + (size_t)(t * 64 + row) * DM + h * 64 + c * 8);
        }
    };
    auto wrK = [&]() {
        #pragma unroll
        for (int p = 0; p < 4; ++p) {
            int u = p * 128 + tid, row = u >> 3, c = u & 7;
            *(bf16x8*)&Kl[(row << 6) + ((c ^ (row & 7)) << 3)] = kreg[p];
        }
    };

    auto qk = [&](f32x16* sdst) {
        #pragma unroll
        for (int ksub = 0; ksub < 2; ++ksub) {
            const int row = ksub * 32 + l31;
            f32x16 a;
            #pragma unroll
            for (int e = 0; e < 16; ++e) a[e] = 0.f;
            #pragma unroll
            for (int kd0 = 0; kd0 < 4; ++kd0) {
                bf16x8 kf = *(const bf16x8*)
                    &Kl[(row << 6) + ((((kd0 << 1) + hi) ^ (row & 7)) << 3)];
                a = __builtin_amdgcn_mfma_f32_32x32x16_bf16(kf, qf[kd0], a, 0, 0, 0);
            }
            sdst[ksub] = a;
        }
    };
    auto mask_sf = [&](f32x16* s, int t) {
        const int kb = (t << 6) + 4 * hi;
        #pragma unroll
        for (int ksub = 0; ksub < 2; ++ksub)
            #pragma unroll
            for (int e = 0; e < 16; ++e) {
                int k = kb + ksub * 32 + ((e & 3) + 8 * (e >> 2));
                if (k > qg) s[ksub][e] = -1e30f;
            }
    };

    // ---- prologue: K(t0)->Kl, V(t0)->Vl[0], V(t0+1)->Vl[1]; S(t0);
    //      then Kl <- K(t0+1) (single-buffer K handoff) ----
    stageK_lds(t0i);
    stageV_lds(t0i, 0);
    const bool multi = (t1i > t0i);
    if (multi) { stageV_lds(t0i + 1, 1); ldK(t0i + 1); }
    __syncthreads();                   // staged data ready (drains all loads)
    f32x16 sf[2], sfn[2];
    qk(sf);                            // reads Kl = K(t0)
    if (t0i == qb) mask_sf(sf, t0i);
    __syncthreads();                   // all waves done reading K(t0)
    if (multi) wrK();                  // Kl <- K(t0+1)
    __syncthreads();

    // loop invariant at top: sf=S(t); Kl=K(t+1); Vl[cur]=V(t); Vl[cur^1]=V(t+1)
    for (int t = t0i; t <= t1i; ++t) {
        const int cur = (t - t0i) & 1;
        const bool have_next  = (t + 1 <= t1i);
        const bool have_next2 = (t + 2 <= t1i);
        // A) issue reg-staged loads for tile t+2 (in flight across whole body)
        if (have_next2) {
            const int t2 = t + 2;
            #pragma unroll
            for (int p = 0; p < 4; ++p) {
                int u   = p * 128 + tid;
                int row = u >> 3;
                int c   = u & 7;
                kreg[p] = *(const bf16x8*)(Kp + (size_t)(t2 * 64 + row) * DM + h * 64 + c * 8);
                vreg[p] = *(const bf16x8*)(Vt + (size_t)(h * 64 + row) * T_SEQ + t2 * 64 + c * 8);
            }
        }
        // B) QK(t+1) — MFMA, independent of softmax(t); reads Kl = K(t+1)
        __builtin_amdgcn_s_setprio(1);
        if (have_next) {
            qk(sfn);
            if (t + 1 == qb) mask_sf(sfn, t + 1);
        }
        __builtin_amdgcn_s_setprio(0);
        // C) softmax(t) — VALU
        float pm;
        {
            float t0[8];
            #pragma unroll
            for (int e = 0; e < 8; ++e)
                t0[e] = fmaxf(fmaxf(sf[0][e], sf[0][e + 8]), fmaxf(sf[1][e], sf[1][e + 8]));
            #pragma unroll
            for (int s = 4; s > 0; s >>= 1)
                #pragma unroll
                for (int e = 0; e < s; ++e) t0[e] = fmaxf(t0[e], t0[e + s]);
            pm = xhalf_max(t0[0]);
        }
        if (pm > m_i + 8.f) {               // defer-max rescale
            float al = exp2f(m_i - pm);
            m_i = pm;
            l_i *= al;
            #pragma unroll
            for (int d = 0; d < 2; ++d)
                #pragma unroll
                for (int e = 0; e < 16; ++e) oacc[d][e] *= al;
        }
        float p[32];
        #pragma unroll
        for (int i = 0; i < 32; ++i)
            p[i] = exp2f(sf[i >> 4][i & 15] - m_i);
        {
            float s0[8];
            #pragma unroll
            for (int e = 0; e < 8; ++e)
                s0[e] = (p[e] + p[e + 8]) + (p[e + 16] + p[e + 24]);
            #pragma unroll
            for (int s = 4; s > 0; s >>= 1)
                #pragma unroll
                for (int e = 0; e < s; ++e) s0[e] += s0[e + s];
            l_i += xhalf_sum(s0[0]);
        }
        // D) PV(t): P->bf16 frags (cvt_pk + permlane32_swap), O^T += V^T P^T
        __builtin_amdgcn_s_setprio(1);
        #pragma unroll
        for (int ks = 0; ks < 4; ++ks) {
            unsigned w0 = cvtpk_bf16(p[8 * ks + 0], p[8 * ks + 1]);
            unsigned w1 = cvtpk_bf16(p[8 * ks + 2], p[8 * ks + 3]);
            unsigned w2 = cvtpk_bf16(p[8 * ks + 4], p[8 * ks + 5]);
            unsigned w3 = cvtpk_bf16(p[8 * ks + 6], p[8 * ks + 7]);
            permswap(w0, w2);
            permswap(w1, w3);
            union { unsigned u[4]; bf16x8 v; } pu;
            pu.u[0] = w0; pu.u[1] = w1; pu.u[2] = w2; pu.u[3] = w3;
            #pragma unroll
            for (int dsub = 0; dsub < 2; ++dsub) {
                const int row = dsub * 32 + l31;
                bf16x8 vt = *(const bf16x8*)
                    &Vl[cur][(row << 6) + ((((ks << 1) + hi) ^ (row & 7)) << 3)];
                oacc[dsub] = __builtin_amdgcn_mfma_f32_32x32x16_bf16(vt, pu.v, oacc[dsub], 0, 0, 0);
            }
        }
        __builtin_amdgcn_s_setprio(0);
        // E) commit K(t+2)->Kl, V(t+2)->Vl[cur] once all reads this iter done
        if (have_next2) {
            __syncthreads();
            wrK();
            #pragma unroll
            for (int p = 0; p < 4; ++p) {
                int u   = p * 128 + tid;
                int row = u >> 3;
                int c   = u & 7;
                *(bf16x8*)&Vl[cur][(row << 6) + ((c ^ (row & 7)) << 3)] = vreg[p];
            }
            __syncthreads();
        }
        if (have_next) {
            sf[0] = sfn[0];
            sf[1] = sfn[1];
        }
    }
    // ---- epilogue: transpose via per-wave LDS, store O (or U,m,l) ----
    __syncthreads();
    __bf16* ow = &Kl[0] + wid * 2048;   // per-wave [32 q][64 d], 16B-swizzled
    const float invl = (nc > 1) ? 1.0f : (1.f / l_i);
    #pragma unroll
    for (int dsub = 0; dsub < 2; ++dsub)
        #pragma unroll
        for (int e = 0; e < 16; ++e) {
            int d = dsub * 32 + ((e & 3) + 8 * (e >> 2)) + 4 * hi;
            float v = oacc[dsub][e] * invl;
            int bo = l31 * 128 + ((2 * d) ^ ((l31 & 7) << 4));
            *(__bf16*)((char*)ow + bo) = (__bf16)v;
        }
    if (nc == 1) {
        #pragma unroll
        for (int i = 0; i < 4; ++i) {
            int u  = hi * 4 + i;
            int bo = l31 * 128 + ((u * 16) ^ ((l31 & 7) << 4));
            bf16x8 v8 = *(const bf16x8*)((char*)ow + bo);
            *(bf16x8*)(O + (size_t)qg * DM + h * 64 + u * 8) = v8;
        }
    } else {
        __bf16* Uc = (chunk == 0) ? U0 : (chunk == 1) ? U1 : U2;
        const int rows  = (chunk == 2) ? C3_ROWS : SPL_ROWS;
        const int ridx  = qg - ((chunk == 2) ? C3_QB * 64 : C2_QB * 64);
        #pragma unroll
        for (int i = 0; i < 4; ++i) {
            int u  = hi * 4 + i;
            int bo = l31 * 128 + ((u * 16) ^ ((l31 & 7) << 4));
            bf16x8 v8 = *(const bf16x8*)((char*)ow + bo);
            *(bf16x8*)(Uc + ((size_t)h * rows + ridx) * 64 + u * 8) = v8;
        }
        if (hi == 0) {
            size_t off = (chunk == 0) ? ((size_t)h * SPL_ROWS + ridx)
                       : (chunk == 1) ? ((size_t)(NH + h) * SPL_ROWS + ridx)
                                      : ((size_t)2 * NH * SPL_ROWS + (size_t)h * C3_ROWS + ridx);
            float* mlp = Ml + off * 2;
            mlp[0] = m_i;
            mlp[1] = l_i;
        }
    }
}

// ---------------- combine 2 or 3 kv-chunks for split rows ----------------
__global__ __launch_bounds__(256)
void attn_combine(const __bf16* __restrict__ U0, const __bf16* __restrict__ U1,
                  const __bf16* __restrict__ U2, const float* __restrict__ Ml,
                  __bf16* __restrict__ O) {
    int gid = blockIdx.x * 256 + threadIdx.x;    // 0 .. SPL_ROWS*NH*8-1
    int rh  = gid >> 3;
    int e8  = gid & 7;
    int ridx = rh >> 4, h = rh & 15;             // ridx in [0, SPL_ROWS)
    int qg   = C2_QB * 64 + ridx;                // global q row
    bool has3 = (qg >= C3_QB * 64);
    const float* ml0 = Ml + ((size_t)h * SPL_ROWS + ridx) * 2;
    const float* ml1 = Ml + ((size_t)(NH + h) * SPL_ROWS + ridx) * 2;
    float m0 = ml0[0], l0 = ml0[1], m1 = ml1[0], l1 = ml1[1];
    float m2 = -1e30f, l2 = 0.f;
    if (has3) {
        const float* ml2 = Ml + ((size_t)2 * NH * SPL_ROWS
                                 + (size_t)h * C3_ROWS + (qg - C3_QB * 64)) * 2;
        m2 = ml2[0]; l2 = ml2[1];
    }
    float M  = fmaxf(fmaxf(m0, m1), m2);
    float s0 = exp2f(m0 - M), s1 = exp2f(m1 - M);
    float s2 = has3 ? exp2f(m2 - M) : 0.f;
    float inv = 1.f / (l0 * s0 + l1 * s1 + l2 * s2);
    bf16x8 u0 = *(const bf16x8*)(U0 + ((size_t)h * SPL_ROWS + ridx) * 64 + e8 * 8);
    bf16x8 u1 = *(const bf16x8*)(U1 + ((size_t)h * SPL_ROWS + ridx) * 64 + e8 * 8);
    bf16x8 o;
    if (has3) {
        bf16x8 u2 = *(const bf16x8*)(U2 + ((size_t)h * C3_ROWS + (qg - C3_QB * 64)) * 64 + e8 * 8);
        #pragma unroll
        for (int j = 0; j < 8; ++j)
            o[j] = (__bf16)((((float)u0[j] * s0 + (float)u1[j] * s1) + (float)u2[j] * s2) * inv);
    } else {
        #pragma unroll
        for (int j = 0; j < 8; ++j)
            o[j] = (__bf16)(((float)u0[j] * s0 + (float)u1[j] * s1) * inv);
    }
    *(bf16x8*)(O + (size_t)qg * DM + h * 64 + e8 * 8) = o;
}

extern "C" void kernel_launch(void* const* d_in, const int* in_sizes, int n_in,
                              void* d_out, int out_size, void* d_ws, size_t ws_size,
                              hipStream_t stream) {
    const float* x  = (const float*)d_in[0];
    const float* Wq = (const float*)d_in[1];
    const float* Wk = (const float*)d_in[2];
    const float* Wv = (const float*)d_in[3];
    const float* Wo = (const float*)d_in[4];
    float* out = (float*)d_out;

    char* ws = (char*)d_ws;
    const size_t MB = (size_t)1 << 20;
    __bf16* xb    = (__bf16*)(ws + 0 * MB);    // 8 MiB (dead after QKV gemms)
    __bf16* U0B   = (__bf16*)(ws + 0 * MB);    // reuses xb: 5.25 MiB
    __bf16* wqb   = (__bf16*)(ws + 8 * MB);    // 2 MiB (dead after qkv)
    float*  MlB   = (float*)(ws + 8 * MB);     // reuses wqb: 0.85 MiB
    __bf16* wkb   = (__bf16*)(ws + 10 * MB);   // dead after qkv
    __bf16* U2B   = (__bf16*)(ws + 10 * MB);   // reuses wkb+wvb: 2.5 MiB
    __bf16* wvb   = (__bf16*)(ws + 12 * MB);
    __bf16* wob   = (__bf16*)(ws + 14 * MB);   // live until gemm_out
    __bf16* Qb    = (__bf16*)(ws + 16 * MB);
    __bf16* Kb    = (__bf16*)(ws + 24 * MB);
    __bf16* Vb    = (__bf16*)(ws + 32 * MB);   // dead after vtrans
    __bf16* U1B   = (__bf16*)(ws + 32 * MB);   // reuses Vb: 5.25 MiB
    __bf16* attnb = (__bf16*)(ws + 40 * MB);
    __bf16* VtR   = (__bf16*)(ws + 48 * MB);   // 8 MiB; total ws usage 56 MiB

    const int nX4 = T_SEQ * DM / 4;
    const int nW4 = DM * DM / 4;
    cvt5_bf16<<<dim3((nX4 + 255) / 256, 5), 256, 0, stream>>>(
        x, Wq, Wk, Wv, Wo, xb, wqb, wkb, wvb, wob, nX4, nW4);

    gemm_qkv<<<dim3(DM / 128, T_SEQ / 128, 3), 256, 0, stream>>>(xb, wqb, wkb, wvb, Qb, Kb, Vb);

    vtrans<<<dim3(T_SEQ / 64, NH), 256, 0, stream>>>(Vb, VtR);

    attn_fwd<<<dim3(NH, NY), 128, 0, stream>>>(Qb, Kb, VtR, attnb, U0B, U1B, U2B, MlB);

    attn_combine<<<(SPL_ROWS * NH * 8) / 256, 256, 0, stream>>>(U0B, U1B, U2B, MlB, attnb);

    gemm_out<<<dim3(DM / 128, T_SEQ / 128), 256, 0, stream>>>(attnb, wob, out);
}

// Round 16
// 163.629 us; speedup vs baseline: 1.2514x; 1.1633x over previous
//
#include <hip/hip_runtime.h>
#include <hip/hip_bf16.h>
#include <math.h>

typedef __attribute__((ext_vector_type(8)))  __bf16 bf16x8;
typedef __attribute__((ext_vector_type(4)))  __bf16 bf16x4;
typedef __attribute__((ext_vector_type(4)))  float  f32x4;
typedef __attribute__((ext_vector_type(16))) float  f32x16;

static constexpr int T_SEQ = 4096;
static constexpr int DM    = 1024;
static constexpr int NH    = 16;
// chunking: q-tile qb is split into nc = ceil((qb+1)/22) kv-chunks (1,2,3)
// rows with qb >= 22 need combine; chunk 2 exists only for qb >= 44
static constexpr int C2_QB    = 22;                   // first 2-chunk q-tile
static constexpr int C3_QB    = 44;                   // first 3-chunk q-tile
static constexpr int SPL_ROWS = T_SEQ - C2_QB * 64;   // 2688 rows needing combine
static constexpr int C3_ROWS  = T_SEQ - C3_QB * 64;   // 1280 rows with a 3rd chunk
// per-head block count: 22 unsplit + 22*2 + 20*3 = 126
static constexpr int NY = 126;
// 1/sqrt(dk) * log2(e): softmax done in exp2 domain
static constexpr float QSCALE = 0.125f * 1.44269504088896340736f;

__device__ __forceinline__ void gload16(const void* g, void* l) {
    __builtin_amdgcn_global_load_lds(
        (const __attribute__((address_space(1))) unsigned int*)g,
        (__attribute__((address_space(3))) unsigned int*)l,
        16, 0, 0);
}

__device__ __forceinline__ unsigned cvtpk_bf16(float a, float b) {
    unsigned r;
    asm("v_cvt_pk_bf16_f32 %0, %1, %2" : "=v"(r) : "v"(a), "v"(b));
    return r;
}
// v_permlane32_swap_b32: exchanges lane<32 / lane>=32 halves between x and y
__device__ __forceinline__ void permswap(unsigned& x, unsigned& y) {
    asm("v_permlane32_swap_b32 %0, %1" : "+v"(x), "+v"(y));
}
// cross-half (lane^32) reduce. The empty asm makes b a distinct SSA value so
// the allocator cannot coalesce a/b into one VGPR (round-5 NaN bug).
__device__ __forceinline__ float xhalf_max(float v) {
    union { float f; unsigned u; } a, b;
    a.f = v; b.f = v;
    asm volatile("" : "+v"(b.u));
    permswap(a.u, b.u);
    return fmaxf(a.f, b.f);
}
__device__ __forceinline__ float xhalf_sum(float v) {
    union { float f; unsigned u; } a, b;
    a.f = v; b.f = v;
    asm volatile("" : "+v"(b.u));
    permswap(a.u, b.u);
    return a.f + b.f;
}

// ---------------- fp32 -> bf16 converts ----------------
__global__ __launch_bounds__(256)
void cvt_bf16(const float* __restrict__ in, __bf16* __restrict__ out, int n4) {
    int i = blockIdx.x * blockDim.x + threadIdx.x;
    if (i >= n4) return;
    float4 v = ((const float4*)in)[i];
    bf16x4 o;
    o[0] = (__bf16)v.x; o[1] = (__bf16)v.y; o[2] = (__bf16)v.z; o[3] = (__bf16)v.w;
    ((bf16x4*)out)[i] = o;
}

__global__ __launch_bounds__(256)
void cvt4_bf16(const float* __restrict__ a0, const float* __restrict__ a1,
               const float* __restrict__ a2, const float* __restrict__ a3,
               __bf16* __restrict__ o0, __bf16* __restrict__ o1,
               __bf16* __restrict__ o2, __bf16* __restrict__ o3, int n4) {
    int i = blockIdx.x * blockDim.x + threadIdx.x;
    if (i >= n4) return;
    const float* in = blockIdx.y == 0 ? a0 : blockIdx.y == 1 ? a1 : blockIdx.y == 2 ? a2 : a3;
    __bf16* out     = blockIdx.y == 0 ? o0 : blockIdx.y == 1 ? o1 : blockIdx.y == 2 ? o2 : o3;
    float4 v = ((const float4*)in)[i];
    bf16x4 o;
    o[0] = (__bf16)v.x; o[1] = (__bf16)v.y; o[2] = (__bf16)v.z; o[3] = (__bf16)v.w;
    ((bf16x4*)out)[i] = o;
}

// ---------------- GEMM body: C = A @ B^T (m97 structure) ----------------
template<bool OUT_BF16>
__device__ __forceinline__ void gemm_body(const __bf16* __restrict__ A,
                                          const __bf16* __restrict__ B,
                                          void* __restrict__ Cout,
                                          int N, int K, float scale,
                                          int bx, int by) {
    __shared__ __align__(16) __bf16 Al[128 * 64];
    __shared__ __align__(16) __bf16 Bl[128 * 64];
    const int tid  = threadIdx.x;
    const int lane = tid & 63;
    const int wid  = tid >> 6;
    const int wr   = wid >> 1, wc = wid & 1;
    const int m0   = by * 128, n0 = bx * 128;
    const int r    = lane & 15, g = lane >> 4;

    f32x4 acc[4][4];
    const f32x4 z4 = {0.f, 0.f, 0.f, 0.f};
    #pragma unroll
    for (int i = 0; i < 4; ++i)
        #pragma unroll
        for (int j = 0; j < 4; ++j) acc[i][j] = z4;

    for (int kt = 0; kt < K; kt += 64) {
        __syncthreads();
        #pragma unroll
        for (int p = 0; p < 4; ++p) {
            int u    = p * 256 + tid;
            int row  = u >> 3;
            int col8 = (u & 7) ^ (row & 7);
            gload16(A + (size_t)(m0 + row) * K + kt + col8 * 8,
                    (char*)Al + (p * 256 + wid * 64) * 16);
            gload16(B + (size_t)(n0 + row) * K + kt + col8 * 8,
                    (char*)Bl + (p * 256 + wid * 64) * 16);
        }
        __syncthreads();
        __builtin_amdgcn_s_setprio(1);
        #pragma unroll
        for (int kk = 0; kk < 2; ++kk) {
            bf16x8 af[4], bfr[4];
            #pragma unroll
            for (int mi = 0; mi < 4; ++mi)
                af[mi] = *(const bf16x8*)&Al[(wr * 64 + mi * 16 + r) * 64 + (((kk * 4 + g) ^ (r & 7)) * 8)];
            #pragma unroll
            for (int nj = 0; nj < 4; ++nj)
                bfr[nj] = *(const bf16x8*)&Bl[(wc * 64 + nj * 16 + r) * 64 + (((kk * 4 + g) ^ (r & 7)) * 8)];
            #pragma unroll
            for (int mi = 0; mi < 4; ++mi)
                #pragma unroll
                for (int nj = 0; nj < 4; ++nj)
                    acc[mi][nj] = __builtin_amdgcn_mfma_f32_16x16x32_bf16(af[mi], bfr[nj], acc[mi][nj], 0, 0, 0);
        }
        __builtin_amdgcn_s_setprio(0);
    }
    #pragma unroll
    for (int mi = 0; mi < 4; ++mi)
        #pragma unroll
        for (int nj = 0; nj < 4; ++nj)
            #pragma unroll
            for (int j = 0; j < 4; ++j) {
                int row = m0 + wr * 64 + mi * 16 + g * 4 + j;
                int col = n0 + wc * 64 + nj * 16 + r;
                float v = acc[mi][nj][j] * scale;
                if (OUT_BF16) ((__bf16*)Cout)[(size_t)row * N + col] = (__bf16)v;
                else          ((float*)Cout)[(size_t)row * N + col]  = v;
            }
}

__global__ __launch_bounds__(256)
void gemm_qkv(const __bf16* __restrict__ A,
              const __bf16* __restrict__ W0, const __bf16* __restrict__ W1,
              const __bf16* __restrict__ W2,
              __bf16* __restrict__ O0, __bf16* __restrict__ O1, __bf16* __restrict__ O2) {
    const int z = blockIdx.z;
    const __bf16* B = z == 0 ? W0 : (z == 1 ? W1 : W2);
    __bf16*       C = z == 0 ? O0 : (z == 1 ? O1 : O2);
    float scale = z == 0 ? QSCALE : 1.0f;
    gemm_body<true>(A, B, C, DM, DM, scale, blockIdx.x, blockIdx.y);
}

__global__ __launch_bounds__(256)
void gemm_out(const __bf16* __restrict__ A, const __bf16* __restrict__ B,
              float* __restrict__ C) {
    gemm_body<false>(A, B, C, DM, DM, 1.0f, blockIdx.x, blockIdx.y);
}

// ---------------- V transpose: Vt[h*64+d][t] = V[t][h*64+d] ----------------
__global__ __launch_bounds__(256)
void vtrans(const __bf16* __restrict__ V, __bf16* __restrict__ Vt) {
    __shared__ __bf16 tl[64][72];
    const int tid = threadIdx.x;
    const int t0  = blockIdx.x * 64;
    const int h   = blockIdx.y;
    #pragma unroll
    for (int p = 0; p < 2; ++p) {
        int c = p * 256 + tid, row = c >> 3, col8 = c & 7;
        *(bf16x8*)&tl[row][col8 * 8] =
            *(const bf16x8*)(V + (size_t)(t0 + row) * DM + h * 64 + col8 * 8);
    }
    __syncthreads();
    #pragma unroll
    for (int p = 0; p < 2; ++p) {
        int c = p * 256 + tid, d = c >> 3, tc8 = c & 7;
        bf16x8 o;
        #pragma unroll
        for (int e = 0; e < 8; ++e) o[e] = tl[tc8 * 8 + e][d];
        *(bf16x8*)(Vt + (size_t)(h * 64 + d) * T_SEQ + t0 + tc8 * 8) = o;
    }
}

// ---------------- causal flash attention v10 ----------------
// EXACT round-7 inner loop (102us proven: reg-staged t+2, QK(t+1) overlap,
// plain max/sum trees, defer-max, 124 VGPR). Only the dispatch changed:
// nc = ceil((qb+1)/22) kv-chunks per q-tile (max block work 33 -> 22 tiles).
__global__ __launch_bounds__(128)
void attn_fwd(const __bf16* __restrict__ Q, const __bf16* __restrict__ Kp,
              const __bf16* __restrict__ Vt, __bf16* __restrict__ O,
              __bf16* __restrict__ U0, __bf16* __restrict__ U1,
              __bf16* __restrict__ U2, float* __restrict__ Ml)
{
    __shared__ __align__(16) __bf16 Kl[2][64 * 64];
    __shared__ __align__(16) __bf16 Vl[2][64 * 64];
    const int tid  = threadIdx.x;
    const int lane = tid & 63, wid = tid >> 6;
    const int l31  = lane & 31;
    const int hi   = lane >> 5;
    const int h    = blockIdx.x;                 // head fastest -> XCD spread
    const int y    = blockIdx.y;                 // heavy chunks dispatched first
    int qb, chunk, nc;
    if (y < 60)       { qb = 63 - y / 3;        chunk = y % 3;        nc = 3; }
    else if (y < 104) { int s = y - 60; qb = 43 - s / 2; chunk = s % 2; nc = 2; }
    else              { qb = 21 - (y - 104);    chunk = 0;            nc = 1; }
    const int n    = qb + 1;
    const int base = n / nc, rem = n % nc;
    const int t0i  = chunk * base + (chunk < rem ? chunk : rem);
    const int t1i  = t0i + base + (chunk < rem ? 1 : 0) - 1;
    const int qw = qb * 64 + wid * 32;           // wave's first q row
    const int qg = qw + l31;                     // this lane's q row

    // Q fragments (B-operand): qf[kd0] = Q[qg][kd0*16 + hi*8 .. +7]
    bf16x8 qf[4];
    #pragma unroll
    for (int kd0 = 0; kd0 < 4; ++kd0)
        qf[kd0] = *(const bf16x8*)(Q + (size_t)qg * DM + h * 64 + kd0 * 16 + hi * 8);

    float m_i = -1e30f, l_i = 0.f;
    f32x16 oacc[2];
    #pragma unroll
    for (int d = 0; d < 2; ++d)
        #pragma unroll
        for (int e = 0; e < 16; ++e) oacc[d][e] = 0.f;

    // prologue: stage first (and second) tile via global_load_lds
    auto stage_lds = [&](int t, int buf) {
        #pragma unroll
        for (int p = 0; p < 4; ++p) {
            int u    = p * 128 + tid;          // 16B unit, 0..511
            int row  = u >> 3;
            int col8 = (u & 7) ^ (row & 7);
            gload16(Kp + (size_t)(t * 64 + row) * DM + h * 64 + col8 * 8,
                    (char*)&Kl[buf][0] + (p * 128 + wid * 64) * 16);
            gload16(Vt + (size_t)(h * 64 + row) * T_SEQ + t * 64 + col8 * 8,
                    (char*)&Vl[buf][0] + (p * 128 + wid * 64) * 16);
        }
    };
    stage_lds(t0i, 0);
    if (t1i > t0i) stage_lds(t0i + 1, 1);
    __syncthreads();

    auto qk = [&](f32x16* sdst, int buf) {
        #pragma unroll
        for (int ksub = 0; ksub < 2; ++ksub) {
            const int row = ksub * 32 + l31;
            f32x16 a;
            #pragma unroll
            for (int e = 0; e < 16; ++e) a[e] = 0.f;
            #pragma unroll
            for (int kd0 = 0; kd0 < 4; ++kd0) {
                bf16x8 kf = *(const bf16x8*)
                    &Kl[buf][(row << 6) + ((((kd0 << 1) + hi) ^ (row & 7)) << 3)];
                a = __builtin_amdgcn_mfma_f32_32x32x16_bf16(kf, qf[kd0], a, 0, 0, 0);
            }
            sdst[ksub] = a;
        }
    };
    auto mask_sf = [&](f32x16* s, int t) {
        const int kb = (t << 6) + 4 * hi;
        #pragma unroll
        for (int ksub = 0; ksub < 2; ++ksub)
            #pragma unroll
            for (int e = 0; e < 16; ++e) {
                int k = kb + ksub * 32 + ((e & 3) + 8 * (e >> 2));
                if (k > qg) s[ksub][e] = -1e30f;
            }
    };

    // sf holds S(t) at loop top
    f32x16 sf[2], sfn[2];
    qk(sf, 0);
    if (t0i == qb) mask_sf(sf, t0i);

    bf16x8 kreg[4], vreg[4];
    for (int t = t0i; t <= t1i; ++t) {
        const int cur = (t - t0i) & 1;
        const bool have_next  = (t + 1 <= t1i);
        const bool have_next2 = (t + 2 <= t1i);
        // A) issue reg-staged loads for tile t+2 (in flight across whole body)
        if (have_next2) {
            const int t2 = t + 2;
            #pragma unroll
            for (int p = 0; p < 4; ++p) {
                int u   = p * 128 + tid;
                int row = u >> 3;
                int c   = u & 7;
                kreg[p] = *(const bf16x8*)(Kp + (size_t)(t2 * 64 + row) * DM + h * 64 + c * 8);
                vreg[p] = *(const bf16x8*)(Vt + (size_t)(h * 64 + row) * T_SEQ + t2 * 64 + c * 8);
            }
        }
        // B) QK(t+1) — MFMA, independent of softmax(t)
        __builtin_amdgcn_s_setprio(1);
        if (have_next) {
            qk(sfn, cur ^ 1);
            if (t + 1 == qb) mask_sf(sfn, t + 1);
        }
        __builtin_amdgcn_s_setprio(0);
        // C) softmax(t) — VALU
        float pm;
        {
            float t0[8];
            #pragma unroll
            for (int e = 0; e < 8; ++e)
                t0[e] = fmaxf(fmaxf(sf[0][e], sf[0][e + 8]), fmaxf(sf[1][e], sf[1][e + 8]));
            #pragma unroll
            for (int s = 4; s > 0; s >>= 1)
                #pragma unroll
                for (int e = 0; e < s; ++e) t0[e] = fmaxf(t0[e], t0[e + s]);
            pm = xhalf_max(t0[0]);
        }
        if (pm > m_i + 8.f) {               // defer-max rescale
            float al = exp2f(m_i - pm);
            m_i = pm;
            l_i *= al;
            #pragma unroll
            for (int d = 0; d < 2; ++d)
                #pragma unroll
                for (int e = 0; e < 16; ++e) oacc[d][e] *= al;
        }
        float p[32];
        #pragma unroll
        for (int i = 0; i < 32; ++i)
            p[i] = exp2f(sf[i >> 4][i & 15] - m_i);
        {
            float s0[8];
            #pragma unroll
            for (int e = 0; e < 8; ++e)
                s0[e] = (p[e] + p[e + 8]) + (p[e + 16] + p[e + 24]);
            #pragma unroll
            for (int s = 4; s > 0; s >>= 1)
                #pragma unroll
                for (int e = 0; e < s; ++e) s0[e] += s0[e + s];
            l_i += xhalf_sum(s0[0]);
        }
        // D) PV(t): P->bf16 frags (cvt_pk + permlane32_swap), O^T += V^T P^T
        __builtin_amdgcn_s_setprio(1);
        #pragma unroll
        for (int ks = 0; ks < 4; ++ks) {
            unsigned w0 = cvtpk_bf16(p[8 * ks + 0], p[8 * ks + 1]);
            unsigned w1 = cvtpk_bf16(p[8 * ks + 2], p[8 * ks + 3]);
            unsigned w2 = cvtpk_bf16(p[8 * ks + 4], p[8 * ks + 5]);
            unsigned w3 = cvtpk_bf16(p[8 * ks + 6], p[8 * ks + 7]);
            permswap(w0, w2);
            permswap(w1, w3);
            union { unsigned u[4]; bf16x8 v; } pu;
            pu.u[0] = w0; pu.u[1] = w1; pu.u[2] = w2; pu.u[3] = w3;
            #pragma unroll
            for (int dsub = 0; dsub < 2; ++dsub) {
                const int row = dsub * 32 + l31;
                bf16x8 vt = *(const bf16x8*)
                    &Vl[cur][(row << 6) + ((((ks << 1) + hi) ^ (row & 7)) << 3)];
                oacc[dsub] = __builtin_amdgcn_mfma_f32_32x32x16_bf16(vt, pu.v, oacc[dsub], 0, 0, 0);
            }
        }
        __builtin_amdgcn_s_setprio(0);
        // E) commit tile t+2 into buf[cur] once all reads of buf[cur] are done
        if (have_next2) {
            __syncthreads();
            #pragma unroll
            for (int p = 0; p < 4; ++p) {
                int u   = p * 128 + tid;
                int row = u >> 3;
                int c   = u & 7;
                *(bf16x8*)&Kl[cur][(row << 6) + ((c ^ (row & 7)) << 3)] = kreg[p];
                *(bf16x8*)&Vl[cur][(row << 6) + ((c ^ (row & 7)) << 3)] = vreg[p];
            }
            __syncthreads();
        }
        if (have_next) {
            sf[0] = sfn[0];
            sf[1] = sfn[1];
        }
    }
    // ---- epilogue: transpose via per-wave LDS, store O (or U,m,l) ----
    __syncthreads();
    __bf16* ow = &Kl[0][0] + wid * 2048;   // per-wave [32 q][64 d], 16B-swizzled
    const float invl = (nc > 1) ? 1.0f : (1.f / l_i);
    #pragma unroll
    for (int dsub = 0; dsub < 2; ++dsub)
        #pragma unroll
        for (int e = 0; e < 16; ++e) {
            int d = dsub * 32 + ((e & 3) + 8 * (e >> 2)) + 4 * hi;
            float v = oacc[dsub][e] * invl;
            int bo = l31 * 128 + ((2 * d) ^ ((l31 & 7) << 4));
            *(__bf16*)((char*)ow + bo) = (__bf16)v;
        }
    if (nc == 1) {
        #pragma unroll
        for (int i = 0; i < 4; ++i) {
            int u  = hi * 4 + i;
            int bo = l31 * 128 + ((u * 16) ^ ((l31 & 7) << 4));
            bf16x8 v8 = *(const bf16x8*)((char*)ow + bo);
            *(bf16x8*)(O + (size_t)qg * DM + h * 64 + u * 8) = v8;
        }
    } else {
        // chunk 0/1 index into SPL_ROWS-sized arrays; chunk 2 into C3_ROWS
        __bf16* Uc = (chunk == 0) ? U0 : (chunk == 1) ? U1 : U2;
        const int rows  = (chunk == 2) ? C3_ROWS : SPL_ROWS;
        const int ridx  = qg - ((chunk == 2) ? C3_QB * 64 : C2_QB * 64);
        #pragma unroll
        for (int i = 0; i < 4; ++i) {
            int u  = hi * 4 + i;
            int bo = l31 * 128 + ((u * 16) ^ ((l31 & 7) << 4));
            bf16x8 v8 = *(const bf16x8*)((char*)ow + bo);
            *(bf16x8*)(Uc + ((size_t)h * rows + ridx) * 64 + u * 8) = v8;
        }
        if (hi == 0) {
            // Ml layout: [chunk0 SPL][chunk1 SPL][chunk2 C3] pairs per (h,row)
            size_t off = (chunk == 0) ? ((size_t)h * SPL_ROWS + (qg - C2_QB * 64))
                       : (chunk == 1) ? ((size_t)NH * SPL_ROWS + (size_t)h * SPL_ROWS + (qg - C2_QB * 64))
                                      : ((size_t)2 * NH * SPL_ROWS + (size_t)h * C3_ROWS + (qg - C3_QB * 64));
            float* mlp = Ml + off * 2;
            mlp[0] = m_i;
            mlp[1] = l_i;
        }
    }
}

// ---------------- combine 2 or 3 kv-chunks for split rows ----------------
__global__ __launch_bounds__(256)
void attn_combine(const __bf16* __restrict__ U0, const __bf16* __restrict__ U1,
                  const __bf16* __restrict__ U2, const float* __restrict__ Ml,
                  __bf16* __restrict__ O) {
    int gid = blockIdx.x * 256 + threadIdx.x;    // 0 .. SPL_ROWS*NH*8-1
    int rh  = gid >> 3;
    int e8  = gid & 7;
    int ridx = rh >> 4, h = rh & 15;             // ridx in [0, SPL_ROWS)
    int qg   = C2_QB * 64 + ridx;                // global q row
    bool has3 = (qg >= C3_QB * 64);
    const float* ml0 = Ml + ((size_t)h * SPL_ROWS + ridx) * 2;
    const float* ml1 = Ml + ((size_t)NH * SPL_ROWS + (size_t)h * SPL_ROWS + ridx) * 2;
    float m0 = ml0[0], l0 = ml0[1], m1 = ml1[0], l1 = ml1[1];
    float m2 = -1e30f, l2 = 0.f;
    if (has3) {
        const float* ml2 = Ml + ((size_t)2 * NH * SPL_ROWS
                                 + (size_t)h * C3_ROWS + (qg - C3_QB * 64)) * 2;
        m2 = ml2[0]; l2 = ml2[1];
    }
    float M  = fmaxf(fmaxf(m0, m1), m2);
    float s0 = exp2f(m0 - M), s1 = exp2f(m1 - M);
    float s2 = has3 ? exp2f(m2 - M) : 0.f;
    float inv = 1.f / (l0 * s0 + l1 * s1 + l2 * s2);
    bf16x8 u0 = *(const bf16x8*)(U0 + ((size_t)h * SPL_ROWS + ridx) * 64 + e8 * 8);
    bf16x8 u1 = *(const bf16x8*)(U1 + ((size_t)h * SPL_ROWS + ridx) * 64 + e8 * 8);
    bf16x8 o;
    if (has3) {
        bf16x8 u2 = *(const bf16x8*)(U2 + ((size_t)h * C3_ROWS + (qg - C3_QB * 64)) * 64 + e8 * 8);
        #pragma unroll
        for (int j = 0; j < 8; ++j)
            o[j] = (__bf16)((((float)u0[j] * s0 + (float)u1[j] * s1) + (float)u2[j] * s2) * inv);
    } else {
        #pragma unroll
        for (int j = 0; j < 8; ++j)
            o[j] = (__bf16)(((float)u0[j] * s0 + (float)u1[j] * s1) * inv);
    }
    *(bf16x8*)(O + (size_t)(C2_QB * 64 + ridx) * DM + h * 64 + e8 * 8) = o;
}

extern "C" void kernel_launch(void* const* d_in, const int* in_sizes, int n_in,
                              void* d_out, int out_size, void* d_ws, size_t ws_size,
                              hipStream_t stream) {
    const float* x  = (const float*)d_in[0];
    const float* Wq = (const float*)d_in[1];
    const float* Wk = (const float*)d_in[2];
    const float* Wv = (const float*)d_in[3];
    const float* Wo = (const float*)d_in[4];
    float* out = (float*)d_out;

    char* ws = (char*)d_ws;
    const size_t MB = (size_t)1 << 20;
    __bf16* xb    = (__bf16*)(ws + 0 * MB);    // 8 MiB (dead after QKV gemms)
    __bf16* U0B   = (__bf16*)(ws + 0 * MB);    // reuses xb: 5.25 MiB
    __bf16* wqb   = (__bf16*)(ws + 8 * MB);    // 2 MiB (dead after qkv)
    float*  MlB   = (float*)(ws + 8 * MB);     // reuses wqb: 0.85 MiB
    __bf16* wkb   = (__bf16*)(ws + 10 * MB);   // dead after qkv
    __bf16* U2B   = (__bf16*)(ws + 10 * MB);   // reuses wkb+wvb: 2.5 MiB
    __bf16* wvb   = (__bf16*)(ws + 12 * MB);
    __bf16* wob   = (__bf16*)(ws + 14 * MB);   // live until gemm_out
    __bf16* Qb    = (__bf16*)(ws + 16 * MB);
    __bf16* Kb    = (__bf16*)(ws + 24 * MB);
    __bf16* Vb    = (__bf16*)(ws + 32 * MB);   // dead after vtrans
    __bf16* U1B   = (__bf16*)(ws + 32 * MB);   // reuses Vb: 5.25 MiB
    __bf16* attnb = (__bf16*)(ws + 40 * MB);
    __bf16* VtR   = (__bf16*)(ws + 48 * MB);   // 8 MiB, total ws usage 56 MiB

    const int nX = T_SEQ * DM / 4;
    const int nW = DM * DM / 4;
    cvt_bf16<<<(nX + 255) / 256, 256, 0, stream>>>(x, xb, nX);
    cvt4_bf16<<<dim3((nW + 255) / 256, 4), 256, 0, stream>>>(Wq, Wk, Wv, Wo,
                                                             wqb, wkb, wvb, wob, nW);

    gemm_qkv<<<dim3(DM / 128, T_SEQ / 128, 3), 256, 0, stream>>>(xb, wqb, wkb, wvb, Qb, Kb, Vb);

    vtrans<<<dim3(T_SEQ / 64, NH), 256, 0, stream>>>(Vb, VtR);

    attn_fwd<<<dim3(NH, NY), 128, 0, stream>>>(Qb, Kb, VtR, attnb, U0B, U1B, U2B, MlB);

    attn_combine<<<(SPL_ROWS * NH * 8) / 256, 256, 0, stream>>>(U0B, U1B, U2B, MlB, attnb);

    gemm_out<<<dim3(DM / 128, T_SEQ / 128), 256, 0, stream>>>(attnb, wob, out);
}

// Round 17
// 162.489 us; speedup vs baseline: 1.2601x; 1.0070x over previous
//
#include <hip/hip_runtime.h>
#include <hip/hip_bf16.h>
#include <math.h>

typedef __attribute__((ext_vector_type(8)))  __bf16 bf16x8;
typedef __attribute__((ext_vector_type(4)))  __bf16 bf16x4;
typedef __attribute__((ext_vector_type(4)))  float  f32x4;
typedef __attribute__((ext_vector_type(16))) float  f32x16;

static constexpr int T_SEQ = 4096;
static constexpr int DM    = 1024;
static constexpr int NH    = 16;
// chunking: q-tile qb is split into nc = ceil((qb+1)/22) kv-chunks (1,2,3)
// rows with qb >= 22 need combine; chunk 2 exists only for qb >= 44
static constexpr int C2_QB    = 22;                   // first 2-chunk q-tile
static constexpr int C3_QB    = 44;                   // first 3-chunk q-tile
static constexpr int SPL_ROWS = T_SEQ - C2_QB * 64;   // 2688 rows needing combine
static constexpr int C3_ROWS  = T_SEQ - C3_QB * 64;   // 1280 rows with a 3rd chunk
// per-head block count: 22 unsplit + 22*2 + 20*3 = 126
static constexpr int NY = 126;
// 1/sqrt(dk) * log2(e): softmax done in exp2 domain
static constexpr float QSCALE = 0.125f * 1.44269504088896340736f;

__device__ __forceinline__ void gload16(const void* g, void* l) {
    __builtin_amdgcn_global_load_lds(
        (const __attribute__((address_space(1))) unsigned int*)g,
        (__attribute__((address_space(3))) unsigned int*)l,
        16, 0, 0);
}

__device__ __forceinline__ unsigned cvtpk_bf16(float a, float b) {
    unsigned r;
    asm("v_cvt_pk_bf16_f32 %0, %1, %2" : "=v"(r) : "v"(a), "v"(b));
    return r;
}
// v_permlane32_swap_b32: exchanges lane<32 / lane>=32 halves between x and y
__device__ __forceinline__ void permswap(unsigned& x, unsigned& y) {
    asm("v_permlane32_swap_b32 %0, %1" : "+v"(x), "+v"(y));
}
// cross-half (lane^32) reduce. The empty asm makes b a distinct SSA value so
// the allocator cannot coalesce a/b into one VGPR (round-5 NaN bug).
__device__ __forceinline__ float xhalf_max(float v) {
    union { float f; unsigned u; } a, b;
    a.f = v; b.f = v;
    asm volatile("" : "+v"(b.u));
    permswap(a.u, b.u);
    return fmaxf(a.f, b.f);
}
__device__ __forceinline__ float xhalf_sum(float v) {
    union { float f; unsigned u; } a, b;
    a.f = v; b.f = v;
    asm volatile("" : "+v"(b.u));
    permswap(a.u, b.u);
    return a.f + b.f;
}

// ---------------- fp32 -> bf16 convert (x + 4 weights in one launch) -------
__global__ __launch_bounds__(256)
void cvt5_bf16(const float* __restrict__ a0, const float* __restrict__ a1,
               const float* __restrict__ a2, const float* __restrict__ a3,
               const float* __restrict__ a4,
               __bf16* __restrict__ o0, __bf16* __restrict__ o1,
               __bf16* __restrict__ o2, __bf16* __restrict__ o3,
               __bf16* __restrict__ o4, int nX4, int nW4) {
    int y = blockIdx.y;
    int n4 = (y == 0) ? nX4 : nW4;
    int i = blockIdx.x * blockDim.x + threadIdx.x;
    if (i >= n4) return;
    const float* in = y == 0 ? a0 : y == 1 ? a1 : y == 2 ? a2 : y == 3 ? a3 : a4;
    __bf16* out     = y == 0 ? o0 : y == 1 ? o1 : y == 2 ? o2 : y == 3 ? o3 : o4;
    float4 v = ((const float4*)in)[i];
    bf16x4 o;
    o[0] = (__bf16)v.x; o[1] = (__bf16)v.y; o[2] = (__bf16)v.z; o[3] = (__bf16)v.w;
    ((bf16x4*)out)[i] = o;
}

// ---------------- GEMM body: C = A @ B^T (m97 structure) ----------------
template<bool OUT_BF16>
__device__ __forceinline__ void gemm_body(const __bf16* __restrict__ A,
                                          const __bf16* __restrict__ B,
                                          void* __restrict__ Cout,
                                          int N, int K, float scale,
                                          int bx, int by) {
    __shared__ __align__(16) __bf16 Al[128 * 64];
    __shared__ __align__(16) __bf16 Bl[128 * 64];
    const int tid  = threadIdx.x;
    const int lane = tid & 63;
    const int wid  = tid >> 6;
    const int wr   = wid >> 1, wc = wid & 1;
    const int m0   = by * 128, n0 = bx * 128;
    const int r    = lane & 15, g = lane >> 4;

    f32x4 acc[4][4];
    const f32x4 z4 = {0.f, 0.f, 0.f, 0.f};
    #pragma unroll
    for (int i = 0; i < 4; ++i)
        #pragma unroll
        for (int j = 0; j < 4; ++j) acc[i][j] = z4;

    for (int kt = 0; kt < K; kt += 64) {
        __syncthreads();
        #pragma unroll
        for (int p = 0; p < 4; ++p) {
            int u    = p * 256 + tid;
            int row  = u >> 3;
            int col8 = (u & 7) ^ (row & 7);
            gload16(A + (size_t)(m0 + row) * K + kt + col8 * 8,
                    (char*)Al + (p * 256 + wid * 64) * 16);
            gload16(B + (size_t)(n0 + row) * K + kt + col8 * 8,
                    (char*)Bl + (p * 256 + wid * 64) * 16);
        }
        __syncthreads();
        __builtin_amdgcn_s_setprio(1);
        #pragma unroll
        for (int kk = 0; kk < 2; ++kk) {
            bf16x8 af[4], bfr[4];
            #pragma unroll
            for (int mi = 0; mi < 4; ++mi)
                af[mi] = *(const bf16x8*)&Al[(wr * 64 + mi * 16 + r) * 64 + (((kk * 4 + g) ^ (r & 7)) * 8)];
            #pragma unroll
            for (int nj = 0; nj < 4; ++nj)
                bfr[nj] = *(const bf16x8*)&Bl[(wc * 64 + nj * 16 + r) * 64 + (((kk * 4 + g) ^ (r & 7)) * 8)];
            #pragma unroll
            for (int mi = 0; mi < 4; ++mi)
                #pragma unroll
                for (int nj = 0; nj < 4; ++nj)
                    acc[mi][nj] = __builtin_amdgcn_mfma_f32_16x16x32_bf16(af[mi], bfr[nj], acc[mi][nj], 0, 0, 0);
        }
        __builtin_amdgcn_s_setprio(0);
    }
    #pragma unroll
    for (int mi = 0; mi < 4; ++mi)
        #pragma unroll
        for (int nj = 0; nj < 4; ++nj)
            #pragma unroll
            for (int j = 0; j < 4; ++j) {
                int row = m0 + wr * 64 + mi * 16 + g * 4 + j;
                int col = n0 + wc * 64 + nj * 16 + r;
                float v = acc[mi][nj][j] * scale;
                if (OUT_BF16) ((__bf16*)Cout)[(size_t)row * N + col] = (__bf16)v;
                else          ((float*)Cout)[(size_t)row * N + col]  = v;
            }
}

__global__ __launch_bounds__(256)
void gemm_qkv(const __bf16* __restrict__ A,
              const __bf16* __restrict__ W0, const __bf16* __restrict__ W1,
              const __bf16* __restrict__ W2,
              __bf16* __restrict__ O0, __bf16* __restrict__ O1, __bf16* __restrict__ O2) {
    const int z = blockIdx.z;
    const __bf16* B = z == 0 ? W0 : (z == 1 ? W1 : W2);
    __bf16*       C = z == 0 ? O0 : (z == 1 ? O1 : O2);
    float scale = z == 0 ? QSCALE : 1.0f;
    gemm_body<true>(A, B, C, DM, DM, scale, blockIdx.x, blockIdx.y);
}

__global__ __launch_bounds__(256)
void gemm_out(const __bf16* __restrict__ A, const __bf16* __restrict__ B,
              float* __restrict__ C) {
    gemm_body<false>(A, B, C, DM, DM, 1.0f, blockIdx.x, blockIdx.y);
}

// ---------------- V transpose: Vt[h*64+d][t] = V[t][h*64+d] ----------------
__global__ __launch_bounds__(256)
void vtrans(const __bf16* __restrict__ V, __bf16* __restrict__ Vt) {
    __shared__ __bf16 tl[64][72];
    const int tid = threadIdx.x;
    const int t0  = blockIdx.x * 64;
    const int h   = blockIdx.y;
    #pragma unroll
    for (int p = 0; p < 2; ++p) {
        int c = p * 256 + tid, row = c >> 3, col8 = c & 7;
        *(bf16x8*)&tl[row][col8 * 8] =
            *(const bf16x8*)(V + (size_t)(t0 + row) * DM + h * 64 + col8 * 8);
    }
    __syncthreads();
    #pragma unroll
    for (int p = 0; p < 2; ++p) {
        int c = p * 256 + tid, d = c >> 3, tc8 = c & 7;
        bf16x8 o;
        #pragma unroll
        for (int e = 0; e < 8; ++e) o[e] = tl[tc8 * 8 + e][d];
        *(bf16x8*)(Vt + (size_t)(h * 64 + d) * T_SEQ + t0 + tc8 * 8) = o;
    }
}

// ---------------- causal flash attention v10 ----------------
// EXACT round-7 inner loop (102us proven: reg-staged t+2, QK(t+1) overlap,
// plain max/sum trees, defer-max, 124 VGPR). Only the dispatch changed:
// nc = ceil((qb+1)/22) kv-chunks per q-tile (max block work 33 -> 22 tiles).
__global__ __launch_bounds__(128)
void attn_fwd(const __bf16* __restrict__ Q, const __bf16* __restrict__ Kp,
              const __bf16* __restrict__ Vt, __bf16* __restrict__ O,
              __bf16* __restrict__ U0, __bf16* __restrict__ U1,
              __bf16* __restrict__ U2, float* __restrict__ Ml)
{
    __shared__ __align__(16) __bf16 Kl[2][64 * 64];
    __shared__ __align__(16) __bf16 Vl[2][64 * 64];
    const int tid  = threadIdx.x;
    const int lane = tid & 63, wid = tid >> 6;
    const int l31  = lane & 31;
    const int hi   = lane >> 5;
    const int h    = blockIdx.x;                 // head fastest -> XCD spread
    const int y    = blockIdx.y;                 // heavy chunks dispatched first
    int qb, chunk, nc;
    if (y < 60)       { qb = 63 - y / 3;        chunk = y % 3;        nc = 3; }
    else if (y < 104) { int s = y - 60; qb = 43 - s / 2; chunk = s % 2; nc = 2; }
    else              { qb = 21 - (y - 104);    chunk = 0;            nc = 1; }
    const int n    = qb + 1;
    const int base = n / nc, rem = n % nc;
    const int t0i  = chunk * base + (chunk < rem ? chunk : rem);
    const int t1i  = t0i + base + (chunk < rem ? 1 : 0) - 1;
    const int qw = qb * 64 + wid * 32;           // wave's first q row
    const int qg = qw + l31;                     // this lane's q row

    // Q fragments (B-operand): qf[kd0] = Q[qg][kd0*16 + hi*8 .. +7]
    bf16x8 qf[4];
    #pragma unroll
    for (int kd0 = 0; kd0 < 4; ++kd0)
        qf[kd0] = *(const bf16x8*)(Q + (size_t)qg * DM + h * 64 + kd0 * 16 + hi * 8);

    float m_i = -1e30f, l_i = 0.f;
    f32x16 oacc[2];
    #pragma unroll
    for (int d = 0; d < 2; ++d)
        #pragma unroll
        for (int e = 0; e < 16; ++e) oacc[d][e] = 0.f;

    // prologue: stage first (and second) tile via global_load_lds
    auto stage_lds = [&](int t, int buf) {
        #pragma unroll
        for (int p = 0; p < 4; ++p) {
            int u    = p * 128 + tid;          // 16B unit, 0..511
            int row  = u >> 3;
            int col8 = (u & 7) ^ (row & 7);
            gload16(Kp + (size_t)(t * 64 + row) * DM + h * 64 + col8 * 8,
                    (char*)&Kl[buf][0] + (p * 128 + wid * 64) * 16);
            gload16(Vt + (size_t)(h * 64 + row) * T_SEQ + t * 64 + col8 * 8,
                    (char*)&Vl[buf][0] + (p * 128 + wid * 64) * 16);
        }
    };
    stage_lds(t0i, 0);
    if (t1i > t0i) stage_lds(t0i + 1, 1);
    __syncthreads();

    auto qk = [&](f32x16* sdst, int buf) {
        #pragma unroll
        for (int ksub = 0; ksub < 2; ++ksub) {
            const int row = ksub * 32 + l31;
            f32x16 a;
            #pragma unroll
            for (int e = 0; e < 16; ++e) a[e] = 0.f;
            #pragma unroll
            for (int kd0 = 0; kd0 < 4; ++kd0) {
                bf16x8 kf = *(const bf16x8*)
                    &Kl[buf][(row << 6) + ((((kd0 << 1) + hi) ^ (row & 7)) << 3)];
                a = __builtin_amdgcn_mfma_f32_32x32x16_bf16(kf, qf[kd0], a, 0, 0, 0);
            }
            sdst[ksub] = a;
        }
    };
    auto mask_sf = [&](f32x16* s, int t) {
        const int kb = (t << 6) + 4 * hi;
        #pragma unroll
        for (int ksub = 0; ksub < 2; ++ksub)
            #pragma unroll
            for (int e = 0; e < 16; ++e) {
                int k = kb + ksub * 32 + ((e & 3) + 8 * (e >> 2));
                if (k > qg) s[ksub][e] = -1e30f;
            }
    };

    // sf holds S(t) at loop top
    f32x16 sf[2], sfn[2];
    qk(sf, 0);
    if (t0i == qb) mask_sf(sf, t0i);

    bf16x8 kreg[4], vreg[4];
    for (int t = t0i; t <= t1i; ++t) {
        const int cur = (t - t0i) & 1;
        const bool have_next  = (t + 1 <= t1i);
        const bool have_next2 = (t + 2 <= t1i);
        // A) issue reg-staged loads for tile t+2 (in flight across whole body)
        if (have_next2) {
            const int t2 = t + 2;
            #pragma unroll
            for (int p = 0; p < 4; ++p) {
                int u   = p * 128 + tid;
                int row = u >> 3;
                int c   = u & 7;
                kreg[p] = *(const bf16x8*)(Kp + (size_t)(t2 * 64 + row) * DM + h * 64 + c * 8);
                vreg[p] = *(const bf16x8*)(Vt + (size_t)(h * 64 + row) * T_SEQ + t2 * 64 + c * 8);
            }
        }
        // B) QK(t+1) — MFMA, independent of softmax(t)
        __builtin_amdgcn_s_setprio(1);
        if (have_next) {
            qk(sfn, cur ^ 1);
            if (t + 1 == qb) mask_sf(sfn, t + 1);
        }
        __builtin_amdgcn_s_setprio(0);
        // C) softmax(t) — VALU
        float pm;
        {
            float t0[8];
            #pragma unroll
            for (int e = 0; e < 8; ++e)
                t0[e] = fmaxf(fmaxf(sf[0][e], sf[0][e + 8]), fmaxf(sf[1][e], sf[1][e + 8]));
            #pragma unroll
            for (int s = 4; s > 0; s >>= 1)
                #pragma unroll
                for (int e = 0; e < s; ++e) t0[e] = fmaxf(t0[e], t0[e + s]);
            pm = xhalf_max(t0[0]);
        }
        if (pm > m_i + 8.f) {               // defer-max rescale
            float al = exp2f(m_i - pm);
            m_i = pm;
            l_i *= al;
            #pragma unroll
            for (int d = 0; d < 2; ++d)
                #pragma unroll
                for (int e = 0; e < 16; ++e) oacc[d][e] *= al;
        }
        float p[32];
        #pragma unroll
        for (int i = 0; i < 32; ++i)
            p[i] = exp2f(sf[i >> 4][i & 15] - m_i);
        {
            float s0[8];
            #pragma unroll
            for (int e = 0; e < 8; ++e)
                s0[e] = (p[e] + p[e + 8]) + (p[e + 16] + p[e + 24]);
            #pragma unroll
            for (int s = 4; s > 0; s >>= 1)
                #pragma unroll
                for (int e = 0; e < s; ++e) s0[e] += s0[e + s];
            l_i += xhalf_sum(s0[0]);
        }
        // D) PV(t): P->bf16 frags (cvt_pk + permlane32_swap), O^T += V^T P^T
        __builtin_amdgcn_s_setprio(1);
        #pragma unroll
        for (int ks = 0; ks < 4; ++ks) {
            unsigned w0 = cvtpk_bf16(p[8 * ks + 0], p[8 * ks + 1]);
            unsigned w1 = cvtpk_bf16(p[8 * ks + 2], p[8 * ks + 3]);
            unsigned w2 = cvtpk_bf16(p[8 * ks + 4], p[8 * ks + 5]);
            unsigned w3 = cvtpk_bf16(p[8 * ks + 6], p[8 * ks + 7]);
            permswap(w0, w2);
            permswap(w1, w3);
            union { unsigned u[4]; bf16x8 v; } pu;
            pu.u[0] = w0; pu.u[1] = w1; pu.u[2] = w2; pu.u[3] = w3;
            #pragma unroll
            for (int dsub = 0; dsub < 2; ++dsub) {
                const int row = dsub * 32 + l31;
                bf16x8 vt = *(const bf16x8*)
                    &Vl[cur][(row << 6) + ((((ks << 1) + hi) ^ (row & 7)) << 3)];
                oacc[dsub] = __builtin_amdgcn_mfma_f32_32x32x16_bf16(vt, pu.v, oacc[dsub], 0, 0, 0);
            }
        }
        __builtin_amdgcn_s_setprio(0);
        // E) commit tile t+2 into buf[cur] once all reads of buf[cur] are done
        if (have_next2) {
            __syncthreads();
            #pragma unroll
            for (int p = 0; p < 4; ++p) {
                int u   = p * 128 + tid;
                int row = u >> 3;
                int c   = u & 7;
                *(bf16x8*)&Kl[cur][(row << 6) + ((c ^ (row & 7)) << 3)] = kreg[p];
                *(bf16x8*)&Vl[cur][(row << 6) + ((c ^ (row & 7)) << 3)] = vreg[p];
            }
            __syncthreads();
        }
        if (have_next) {
            sf[0] = sfn[0];
            sf[1] = sfn[1];
        }
    }
    // ---- epilogue: transpose via per-wave LDS, store O (or U,m,l) ----
    __syncthreads();
    __bf16* ow = &Kl[0][0] + wid * 2048;   // per-wave [32 q][64 d], 16B-swizzled
    const float invl = (nc > 1) ? 1.0f : (1.f / l_i);
    #pragma unroll
    for (int dsub = 0; dsub < 2; ++dsub)
        #pragma unroll
        for (int e = 0; e < 16; ++e) {
            int d = dsub * 32 + ((e & 3) + 8 * (e >> 2)) + 4 * hi;
            float v = oacc[dsub][e] * invl;
            int bo = l31 * 128 + ((2 * d) ^ ((l31 & 7) << 4));
            *(__bf16*)((char*)ow + bo) = (__bf16)v;
        }
    if (nc == 1) {
        #pragma unroll
        for (int i = 0; i < 4; ++i) {
            int u  = hi * 4 + i;
            int bo = l31 * 128 + ((u * 16) ^ ((l31 & 7) << 4));
            bf16x8 v8 = *(const bf16x8*)((char*)ow + bo);
            *(bf16x8*)(O + (size_t)qg * DM + h * 64 + u * 8) = v8;
        }
    } else {
        // chunk 0/1 index into SPL_ROWS-sized arrays; chunk 2 into C3_ROWS
        __bf16* Uc = (chunk == 0) ? U0 : (chunk == 1) ? U1 : U2;
        const int rows  = (chunk == 2) ? C3_ROWS : SPL_ROWS;
        const int ridx  = qg - ((chunk == 2) ? C3_QB * 64 : C2_QB * 64);
        #pragma unroll
        for (int i = 0; i < 4; ++i) {
            int u  = hi * 4 + i;
            int bo = l31 * 128 + ((u * 16) ^ ((l31 & 7) << 4));
            bf16x8 v8 = *(const bf16x8*)((char*)ow + bo);
            *(bf16x8*)(Uc + ((size_t)h * rows + ridx) * 64 + u * 8) = v8;
        }
        if (hi == 0) {
            // Ml layout: [chunk0 SPL][chunk1 SPL][chunk2 C3] pairs per (h,row)
            size_t off = (chunk == 0) ? ((size_t)h * SPL_ROWS + (qg - C2_QB * 64))
                       : (chunk == 1) ? ((size_t)NH * SPL_ROWS + (size_t)h * SPL_ROWS + (qg - C2_QB * 64))
                                      : ((size_t)2 * NH * SPL_ROWS + (size_t)h * C3_ROWS + (qg - C3_QB * 64));
            float* mlp = Ml + off * 2;
            mlp[0] = m_i;
            mlp[1] = l_i;
        }
    }
}

// ---------------- combine 2 or 3 kv-chunks for split rows ----------------
__global__ __launch_bounds__(256)
void attn_combine(const __bf16* __restrict__ U0, const __bf16* __restrict__ U1,
                  const __bf16* __restrict__ U2, const float* __restrict__ Ml,
                  __bf16* __restrict__ O) {
    int gid = blockIdx.x * 256 + threadIdx.x;    // 0 .. SPL_ROWS*NH*8-1
    int rh  = gid >> 3;
    int e8  = gid & 7;
    int ridx = rh >> 4, h = rh & 15;             // ridx in [0, SPL_ROWS)
    int qg   = C2_QB * 64 + ridx;                // global q row
    bool has3 = (qg >= C3_QB * 64);
    const float* ml0 = Ml + ((size_t)h * SPL_ROWS + ridx) * 2;
    const float* ml1 = Ml + ((size_t)NH * SPL_ROWS + (size_t)h * SPL_ROWS + ridx) * 2;
    float m0 = ml0[0], l0 = ml0[1], m1 = ml1[0], l1 = ml1[1];
    float m2 = -1e30f, l2 = 0.f;
    if (has3) {
        const float* ml2 = Ml + ((size_t)2 * NH * SPL_ROWS
                                 + (size_t)h * C3_ROWS + (qg - C3_QB * 64)) * 2;
        m2 = ml2[0]; l2 = ml2[1];
    }
    float M  = fmaxf(fmaxf(m0, m1), m2);
    float s0 = exp2f(m0 - M), s1 = exp2f(m1 - M);
    float s2 = has3 ? exp2f(m2 - M) : 0.f;
    float inv = 1.f / (l0 * s0 + l1 * s1 + l2 * s2);
    bf16x8 u0 = *(const bf16x8*)(U0 + ((size_t)h * SPL_ROWS + ridx) * 64 + e8 * 8);
    bf16x8 u1 = *(const bf16x8*)(U1 + ((size_t)h * SPL_ROWS + ridx) * 64 + e8 * 8);
    bf16x8 o;
    if (has3) {
        bf16x8 u2 = *(const bf16x8*)(U2 + ((size_t)h * C3_ROWS + (qg - C3_QB * 64)) * 64 + e8 * 8);
        #pragma unroll
        for (int j = 0; j < 8; ++j)
            o[j] = (__bf16)((((float)u0[j] * s0 + (float)u1[j] * s1) + (float)u2[j] * s2) * inv);
    } else {
        #pragma unroll
        for (int j = 0; j < 8; ++j)
            o[j] = (__bf16)(((float)u0[j] * s0 + (float)u1[j] * s1) * inv);
    }
    *(bf16x8*)(O + (size_t)(C2_QB * 64 + ridx) * DM + h * 64 + e8 * 8) = o;
}

extern "C" void kernel_launch(void* const* d_in, const int* in_sizes, int n_in,
                              void* d_out, int out_size, void* d_ws, size_t ws_size,
                              hipStream_t stream) {
    const float* x  = (const float*)d_in[0];
    const float* Wq = (const float*)d_in[1];
    const float* Wk = (const float*)d_in[2];
    const float* Wv = (const float*)d_in[3];
    const float* Wo = (const float*)d_in[4];
    float* out = (float*)d_out;

    char* ws = (char*)d_ws;
    const size_t MB = (size_t)1 << 20;
    __bf16* xb    = (__bf16*)(ws + 0 * MB);    // 8 MiB (dead after QKV gemms)
    __bf16* U0B   = (__bf16*)(ws + 0 * MB);    // reuses xb: 5.25 MiB
    __bf16* wqb   = (__bf16*)(ws + 8 * MB);    // 2 MiB (dead after qkv)
    float*  MlB   = (float*)(ws + 8 * MB);     // reuses wqb: 0.85 MiB
    __bf16* wkb   = (__bf16*)(ws + 10 * MB);   // dead after qkv
    __bf16* U2B   = (__bf16*)(ws + 10 * MB);   // reuses wkb+wvb: 2.5 MiB
    __bf16* wvb   = (__bf16*)(ws + 12 * MB);
    __bf16* wob   = (__bf16*)(ws + 14 * MB);   // live until gemm_out
    __bf16* Qb    = (__bf16*)(ws + 16 * MB);
    __bf16* Kb    = (__bf16*)(ws + 24 * MB);
    __bf16* Vb    = (__bf16*)(ws + 32 * MB);   // dead after vtrans
    __bf16* U1B   = (__bf16*)(ws + 32 * MB);   // reuses Vb: 5.25 MiB
    __bf16* attnb = (__bf16*)(ws + 40 * MB);
    __bf16* VtR   = (__bf16*)(ws + 48 * MB);   // 8 MiB, total ws usage 56 MiB

    const int nX4 = T_SEQ * DM / 4;
    const int nW4 = DM * DM / 4;
    cvt5_bf16<<<dim3((nX4 + 255) / 256, 5), 256, 0, stream>>>(
        x, Wq, Wk, Wv, Wo, xb, wqb, wkb, wvb, wob, nX4, nW4);

    gemm_qkv<<<dim3(DM / 128, T_SEQ / 128, 3), 256, 0, stream>>>(xb, wqb, wkb, wvb, Qb, Kb, Vb);

    vtrans<<<dim3(T_SEQ / 64, NH), 256, 0, stream>>>(Vb, VtR);

    attn_fwd<<<dim3(NH, NY), 128, 0, stream>>>(Qb, Kb, VtR, attnb, U0B, U1B, U2B, MlB);

    attn_combine<<<(SPL_ROWS * NH * 8) / 256, 256, 0, stream>>>(U0B, U1B, U2B, MlB, attnb);

    gemm_out<<<dim3(DM / 128, T_SEQ / 128), 256, 0, stream>>>(attnb, wob, out);
}